// Round 1
// baseline (691.409 us; speedup 1.0000x reference)
//
#include <hip/hip_runtime.h>
#include <hip/hip_bf16.h>

// GCN 3-layer fused pipeline for MI355X.
// Strategy: aggregate-then-transform ( Â(xW) == (Âx)W ), CSR built per call
// (deterministic), BN+ReLU folded into the next gather as per-feature a*x+c.

#define FD 64            // feature dim
#define EPSF 1e-5f

// ---------------- edge width detection (int64 vs int32) ----------------
__global__ void detect64_kernel(const int* __restrict__ ei, int* __restrict__ flag) {
  if (threadIdx.x == 0 && blockIdx.x == 0) {
    int all0 = 1;
    for (int i = 0; i < 128; ++i) {
      if (ei[2 * i + 1] != 0) { all0 = 0; break; }
    }
    *flag = all0;  // 1 => data is int64 little-endian, read low words at stride 2
  }
}

// ---------------- degree count ----------------
__global__ __launch_bounds__(256) void deg_kernel(const int* __restrict__ ei, int E,
                                                  const int* __restrict__ flag,
                                                  int* __restrict__ deg) {
  int e = blockIdx.x * 256 + threadIdx.x;
  if (e >= E) return;
  const int is64 = *flag;
  int d = is64 ? ei[2 * (E + e)] : ei[E + e];
  atomicAdd(&deg[d], 1);
}

// ---------------- dinv = rsqrt(deg + 1self) ----------------
__global__ __launch_bounds__(256) void dinv_kernel(const int* __restrict__ deg,
                                                   float* __restrict__ dinv, int N) {
  int i = blockIdx.x * 256 + threadIdx.x;
  if (i < N) dinv[i] = rsqrtf((float)(deg[i] + 1));
}

// ---------------- exclusive scan (3 kernels) ----------------
__global__ __launch_bounds__(1024) void scan1_kernel(const int* __restrict__ deg,
                                                     int* __restrict__ rowptr,
                                                     int* __restrict__ partial, int N) {
  __shared__ int lds[1024];
  int i = blockIdx.x * 1024 + threadIdx.x;
  int v = (i < N) ? deg[i] : 0;
  lds[threadIdx.x] = v;
  __syncthreads();
  for (int off = 1; off < 1024; off <<= 1) {
    int t = (threadIdx.x >= (unsigned)off) ? lds[threadIdx.x - off] : 0;
    __syncthreads();
    lds[threadIdx.x] += t;
    __syncthreads();
  }
  if (i < N) rowptr[i + 1] = lds[threadIdx.x];      // inclusive, shifted by 1
  if (threadIdx.x == 1023) partial[blockIdx.x] = lds[1023];
}

__global__ __launch_bounds__(128) void scan2_kernel(int* __restrict__ partial, int B) {
  __shared__ int lds[128];
  int t = threadIdx.x;
  int v = (t < B) ? partial[t] : 0;
  lds[t] = v;
  __syncthreads();
  for (int off = 1; off < 128; off <<= 1) {
    int tv = (t >= off) ? lds[t - off] : 0;
    __syncthreads();
    lds[t] += tv;
    __syncthreads();
  }
  if (t < B) partial[t] = lds[t] - v;               // exclusive
}

__global__ __launch_bounds__(1024) void scan3_kernel(const int* __restrict__ deg,
                                                     int* __restrict__ rowptr,
                                                     const int* __restrict__ partial,
                                                     int* __restrict__ cursor, int N) {
  int i = blockIdx.x * 1024 + threadIdx.x;
  if (i < N) {
    int r = rowptr[i + 1] + partial[blockIdx.x];
    rowptr[i + 1] = r;
    cursor[i] = r - deg[i];                          // = final rowptr[i]
    if (i == 0) rowptr[0] = 0;
  }
}

// ---------------- CSR fill ----------------
__global__ __launch_bounds__(256) void fill_kernel(const int* __restrict__ ei, int E,
                                                   const int* __restrict__ flag,
                                                   const float* __restrict__ dinv,
                                                   int* __restrict__ cursor,
                                                   int2* __restrict__ colw) {
  int e = blockIdx.x * 256 + threadIdx.x;
  if (e >= E) return;
  const int is64 = *flag;
  int s = is64 ? ei[2 * e] : ei[e];
  int d = is64 ? ei[2 * (E + e)] : ei[E + e];
  int slot = atomicAdd(&cursor[d], 1);
  colw[slot] = make_int2(s, __float_as_int(dinv[s] * dinv[d]));
}

// ---------------- aggregation: out[dst] = dinv[dst]^2 * f(H[dst]) + sum w * f(H[src]) ----
// f = identity (layer 1 input) or relu(a*x + c) (BN+ReLU of previous conv)
template <bool BN>
__global__ __launch_bounds__(256) void agg_kernel(const float* __restrict__ H,
                                                  const int* __restrict__ rowptr,
                                                  const int2* __restrict__ colw,
                                                  const float* __restrict__ dinv,
                                                  const float* __restrict__ stats,  // [128]: sum, sumsq
                                                  const float* __restrict__ g,
                                                  const float* __restrict__ be,
                                                  float* __restrict__ out, int N) {
  const int lane = threadIdx.x & 63;
  const int wid = threadIdx.x >> 6;
  const int dst = blockIdx.x * 4 + wid;
  if (dst >= N) return;

  float a = 1.f, c = 0.f;
  if (BN) {
    float invN = 1.0f / (float)N;
    float m = stats[lane] * invN;
    float v = stats[64 + lane] * invN - m * m;
    float r = rsqrtf(v + EPSF);
    a = g[lane] * r;
    c = be[lane] - m * a;
  }

  const float di = dinv[dst];
  float hd = H[dst * FD + lane];
  if (BN) hd = fmaxf(fmaf(a, hd, c), 0.f);
  float acc0 = di * di * hd;
  float acc1 = 0.f;

  const int e0 = rowptr[dst], e1 = rowptr[dst + 1];
  int e = e0;
  for (; e + 1 < e1; e += 2) {
    int2 cw0 = colw[e];
    int2 cw1 = colw[e + 1];
    float h0 = H[cw0.x * FD + lane];
    float h1 = H[cw1.x * FD + lane];
    if (BN) {
      h0 = fmaxf(fmaf(a, h0, c), 0.f);
      h1 = fmaxf(fmaf(a, h1, c), 0.f);
    }
    acc0 = fmaf(__int_as_float(cw0.y), h0, acc0);
    acc1 = fmaf(__int_as_float(cw1.y), h1, acc1);
  }
  if (e < e1) {
    int2 cw = colw[e];
    float h0 = H[cw.x * FD + lane];
    if (BN) h0 = fmaxf(fmaf(a, h0, c), 0.f);
    acc0 = fmaf(__int_as_float(cw.y), h0, acc0);
  }
  out[dst * FD + lane] = acc0 + acc1;
}

// ---------------- GEMM: out = A @ W + b  (A: [N,64], W: [64,64]) -------------
// lane = output column; W column lives in 64 VGPRs; rows broadcast.
// Optionally accumulates per-feature sum/sumsq (for BN) lane-locally.
#define ROWS_PER_WAVE 16
template <bool STATS>
__global__ __launch_bounds__(256) void gemm_kernel(const float* __restrict__ A,
                                                   const float* __restrict__ W,
                                                   const float* __restrict__ bias,
                                                   float* __restrict__ out,
                                                   float* __restrict__ stats, int N) {
  const int lane = threadIdx.x & 63;
  const int wid = threadIdx.x >> 6;

  float wreg[FD];
#pragma unroll
  for (int k = 0; k < FD; ++k) wreg[k] = W[k * FD + lane];
  const float bl = bias[lane];

  float s1 = 0.f, s2 = 0.f;
  const int row0 = (blockIdx.x * 4 + wid) * ROWS_PER_WAVE;
  for (int r = 0; r < ROWS_PER_WAVE; ++r) {
    const int row = row0 + r;
    if (row >= N) break;
    const float4* __restrict__ xr = (const float4*)(A + (size_t)row * FD);
    float acc = 0.f;
#pragma unroll
    for (int k4 = 0; k4 < FD / 4; ++k4) {
      float4 xv = xr[k4];
      acc = fmaf(xv.x, wreg[4 * k4 + 0], acc);
      acc = fmaf(xv.y, wreg[4 * k4 + 1], acc);
      acc = fmaf(xv.z, wreg[4 * k4 + 2], acc);
      acc = fmaf(xv.w, wreg[4 * k4 + 3], acc);
    }
    float o = acc + bl;
    out[(size_t)row * FD + lane] = o;
    if (STATS) {
      s1 += o;
      s2 += o * o;
    }
  }

  if (STATS) {
    __shared__ float ls1[256];
    __shared__ float ls2[256];
    ls1[threadIdx.x] = s1;
    ls2[threadIdx.x] = s2;
    __syncthreads();
    if (threadIdx.x < 64) {
      float a1 = ls1[threadIdx.x] + ls1[threadIdx.x + 64] + ls1[threadIdx.x + 128] +
                 ls1[threadIdx.x + 192];
      float a2 = ls2[threadIdx.x] + ls2[threadIdx.x + 64] + ls2[threadIdx.x + 128] +
                 ls2[threadIdx.x + 192];
      atomicAdd(&stats[threadIdx.x], a1);
      atomicAdd(&stats[64 + threadIdx.x], a2);
    }
  }
}

extern "C" void kernel_launch(void* const* d_in, const int* in_sizes, int n_in,
                              void* d_out, int out_size, void* d_ws, size_t ws_size,
                              hipStream_t stream) {
  const float* x = (const float*)d_in[0];
  const int* ei = (const int*)d_in[1];
  const float* W1 = (const float*)d_in[2];
  const float* b1 = (const float*)d_in[3];
  const float* g1 = (const float*)d_in[4];
  const float* be1 = (const float*)d_in[5];
  const float* W2 = (const float*)d_in[6];
  const float* b2 = (const float*)d_in[7];
  const float* g2 = (const float*)d_in[8];
  const float* be2 = (const float*)d_in[9];
  const float* W3 = (const float*)d_in[10];
  const float* b3 = (const float*)d_in[11];

  const int N = in_sizes[0] / FD;
  const int E = in_sizes[1] / 2;

  // ---- workspace carve-up (256B aligned) ----
  char* p = (char*)d_ws;
  auto alloc = [&](size_t bytes) {
    char* r = p;
    p += (bytes + 255) & ~(size_t)255;
    return r;
  };
  int* flag = (int*)alloc(4);
  float* stats1 = (float*)alloc(128 * 4);
  float* stats2 = (float*)alloc(128 * 4);
  int* partial = (int*)alloc(128 * 4);
  int* deg = (int*)alloc((size_t)N * 4);
  float* dinv = (float*)alloc((size_t)N * 4);
  int* rowptr = (int*)alloc((size_t)(N + 1) * 4);
  int* cursor = (int*)alloc((size_t)N * 4);
  int2* colw = (int2*)alloc((size_t)E * 8);
  float* bufA = (float*)alloc((size_t)N * FD * 4);
  float* bufB = (float*)alloc((size_t)N * FD * 4);
  (void)ws_size;

  hipMemsetAsync(deg, 0, (size_t)N * 4, stream);
  hipMemsetAsync(stats1, 0, 128 * 4, stream);
  hipMemsetAsync(stats2, 0, 128 * 4, stream);

  const int NB = (N + 1023) / 1024;  // 98 for N=100000, must be <= 128

  detect64_kernel<<<1, 64, 0, stream>>>(ei, flag);
  deg_kernel<<<(E + 255) / 256, 256, 0, stream>>>(ei, E, flag, deg);
  dinv_kernel<<<(N + 255) / 256, 256, 0, stream>>>(deg, dinv, N);
  scan1_kernel<<<NB, 1024, 0, stream>>>(deg, rowptr, partial, N);
  scan2_kernel<<<1, 128, 0, stream>>>(partial, NB);
  scan3_kernel<<<NB, 1024, 0, stream>>>(deg, rowptr, partial, cursor, N);
  fill_kernel<<<(E + 255) / 256, 256, 0, stream>>>(ei, E, flag, dinv, cursor, colw);

  const int aggGrid = (N + 3) / 4;
  const int gemmGrid = (N + 4 * ROWS_PER_WAVE - 1) / (4 * ROWS_PER_WAVE);

  // layer 1: agg(x) -> bufA ; bufA @ W1 + b1 -> bufB (+stats1)
  agg_kernel<false><<<aggGrid, 256, 0, stream>>>(x, rowptr, colw, dinv, nullptr, nullptr,
                                                 nullptr, bufA, N);
  gemm_kernel<true><<<gemmGrid, 256, 0, stream>>>(bufA, W1, b1, bufB, stats1, N);

  // layer 2: agg(relu(bn1(bufB))) -> bufA ; bufA @ W2 + b2 -> bufB (+stats2)
  agg_kernel<true><<<aggGrid, 256, 0, stream>>>(bufB, rowptr, colw, dinv, stats1, g1, be1,
                                                bufA, N);
  gemm_kernel<true><<<gemmGrid, 256, 0, stream>>>(bufA, W2, b2, bufB, stats2, N);

  // layer 3: agg(relu(bn2(bufB))) -> bufA ; bufA @ W3 + b3 -> d_out
  agg_kernel<true><<<aggGrid, 256, 0, stream>>>(bufB, rowptr, colw, dinv, stats2, g2, be2,
                                                bufA, N);
  gemm_kernel<false><<<gemmGrid, 256, 0, stream>>>(bufA, W3, b3, (float*)d_out, nullptr, N);
}

// Round 2
// 576.827 us; speedup vs baseline: 1.1986x; 1.1986x over previous
//
#include <hip/hip_runtime.h>
#include <hip/hip_bf16.h>

// GCN 3-layer fused pipeline for MI355X.
// Strategy: aggregate-then-transform ( Â(xW) == (Âx)W ), CSR built per call
// (deterministic), BN+ReLU folded into the next gather as per-feature a*x+c.
// R2: agg 4-edge unroll (4 independent gather chains / wave), wave-uniform
// rowptr via readfirstlane, parallel int64-detect.

#define FD 64            // feature dim
#define EPSF 1e-5f

// ---------------- edge width detection (int64 vs int32) ----------------
// int64 little-endian => every odd int32 word of the first 64 entries is 0.
__global__ void detect64_kernel(const int* __restrict__ ei, int* __restrict__ flag) {
  int lane = threadIdx.x;
  int v = ei[2 * lane + 1];
  unsigned long long nz = __ballot(v != 0);
  if (lane == 0) *flag = (nz == 0ull) ? 1 : 0;
}

// ---------------- degree count ----------------
__global__ __launch_bounds__(256) void deg_kernel(const int* __restrict__ ei, int E,
                                                  const int* __restrict__ flag,
                                                  int* __restrict__ deg) {
  int e = blockIdx.x * 256 + threadIdx.x;
  if (e >= E) return;
  const int is64 = *flag;
  int d = is64 ? ei[2 * (E + e)] : ei[E + e];
  atomicAdd(&deg[d], 1);
}

// ---------------- dinv = rsqrt(deg + 1self) ----------------
__global__ __launch_bounds__(256) void dinv_kernel(const int* __restrict__ deg,
                                                   float* __restrict__ dinv, int N) {
  int i = blockIdx.x * 256 + threadIdx.x;
  if (i < N) dinv[i] = rsqrtf((float)(deg[i] + 1));
}

// ---------------- exclusive scan (3 kernels) ----------------
__global__ __launch_bounds__(1024) void scan1_kernel(const int* __restrict__ deg,
                                                     int* __restrict__ rowptr,
                                                     int* __restrict__ partial, int N) {
  __shared__ int lds[1024];
  int i = blockIdx.x * 1024 + threadIdx.x;
  int v = (i < N) ? deg[i] : 0;
  lds[threadIdx.x] = v;
  __syncthreads();
  for (int off = 1; off < 1024; off <<= 1) {
    int t = (threadIdx.x >= (unsigned)off) ? lds[threadIdx.x - off] : 0;
    __syncthreads();
    lds[threadIdx.x] += t;
    __syncthreads();
  }
  if (i < N) rowptr[i + 1] = lds[threadIdx.x];      // inclusive, shifted by 1
  if (threadIdx.x == 1023) partial[blockIdx.x] = lds[1023];
}

__global__ __launch_bounds__(128) void scan2_kernel(int* __restrict__ partial, int B) {
  __shared__ int lds[128];
  int t = threadIdx.x;
  int v = (t < B) ? partial[t] : 0;
  lds[t] = v;
  __syncthreads();
  for (int off = 1; off < 128; off <<= 1) {
    int tv = (t >= off) ? lds[t - off] : 0;
    __syncthreads();
    lds[t] += tv;
    __syncthreads();
  }
  if (t < B) partial[t] = lds[t] - v;               // exclusive
}

__global__ __launch_bounds__(1024) void scan3_kernel(const int* __restrict__ deg,
                                                     int* __restrict__ rowptr,
                                                     const int* __restrict__ partial,
                                                     int* __restrict__ cursor, int N) {
  int i = blockIdx.x * 1024 + threadIdx.x;
  if (i < N) {
    int r = rowptr[i + 1] + partial[blockIdx.x];
    rowptr[i + 1] = r;
    cursor[i] = r - deg[i];                          // = final rowptr[i]
    if (i == 0) rowptr[0] = 0;
  }
}

// ---------------- CSR fill ----------------
__global__ __launch_bounds__(256) void fill_kernel(const int* __restrict__ ei, int E,
                                                   const int* __restrict__ flag,
                                                   const float* __restrict__ dinv,
                                                   int* __restrict__ cursor,
                                                   int2* __restrict__ colw) {
  int e = blockIdx.x * 256 + threadIdx.x;
  if (e >= E) return;
  const int is64 = *flag;
  int s = is64 ? ei[2 * e] : ei[e];
  int d = is64 ? ei[2 * (E + e)] : ei[E + e];
  int slot = atomicAdd(&cursor[d], 1);
  colw[slot] = make_int2(s, __float_as_int(dinv[s] * dinv[d]));
}

// ---------------- aggregation: out[dst] = dinv[dst]^2 * f(H[dst]) + sum w * f(H[src]) ----
// f = identity (layer 1 input) or relu(a*x + c) (BN+ReLU of previous conv).
// One wave per dst, lane = feature. 4-edge unroll => 4 independent gather
// chains in flight per wave (latency-bound fix, R2).
template <bool BN>
__global__ __launch_bounds__(256) void agg_kernel(const float* __restrict__ H,
                                                  const int* __restrict__ rowptr,
                                                  const int2* __restrict__ colw,
                                                  const float* __restrict__ dinv,
                                                  const float* __restrict__ stats,  // [128]: sum, sumsq
                                                  const float* __restrict__ g,
                                                  const float* __restrict__ be,
                                                  float* __restrict__ out, int N) {
  const int lane = threadIdx.x & 63;
  const int wid = threadIdx.x >> 6;
  const int dst = blockIdx.x * 4 + wid;
  if (dst >= N) return;

  float a = 1.f, c = 0.f;
  if (BN) {
    float invN = 1.0f / (float)N;
    float m = stats[lane] * invN;
    float v = stats[64 + lane] * invN - m * m;
    float r = rsqrtf(v + EPSF);
    a = g[lane] * r;
    c = be[lane] - m * a;
  }

  const float di = dinv[dst];
  float hd = H[dst * FD + lane];
  if (BN) hd = fmaxf(fmaf(a, hd, c), 0.f);
  float acc0 = di * di * hd;
  float acc1 = 0.f, acc2 = 0.f, acc3 = 0.f;

  // wave-uniform row bounds -> scalar loads for colw, frees vector pipe
  const int e0 = __builtin_amdgcn_readfirstlane(rowptr[dst]);
  const int e1 = __builtin_amdgcn_readfirstlane(rowptr[dst + 1]);
  int e = e0;
  for (; e + 3 < e1; e += 4) {
    int2 cw0 = colw[e];
    int2 cw1 = colw[e + 1];
    int2 cw2 = colw[e + 2];
    int2 cw3 = colw[e + 3];
    float h0 = H[cw0.x * FD + lane];
    float h1 = H[cw1.x * FD + lane];
    float h2 = H[cw2.x * FD + lane];
    float h3 = H[cw3.x * FD + lane];
    if (BN) {
      h0 = fmaxf(fmaf(a, h0, c), 0.f);
      h1 = fmaxf(fmaf(a, h1, c), 0.f);
      h2 = fmaxf(fmaf(a, h2, c), 0.f);
      h3 = fmaxf(fmaf(a, h3, c), 0.f);
    }
    acc0 = fmaf(__int_as_float(cw0.y), h0, acc0);
    acc1 = fmaf(__int_as_float(cw1.y), h1, acc1);
    acc2 = fmaf(__int_as_float(cw2.y), h2, acc2);
    acc3 = fmaf(__int_as_float(cw3.y), h3, acc3);
  }
  for (; e < e1; ++e) {
    int2 cw = colw[e];
    float h0 = H[cw.x * FD + lane];
    if (BN) h0 = fmaxf(fmaf(a, h0, c), 0.f);
    acc0 = fmaf(__int_as_float(cw.y), h0, acc0);
  }
  out[dst * FD + lane] = (acc0 + acc1) + (acc2 + acc3);
}

// ---------------- GEMM: out = A @ W + b  (A: [N,64], W: [64,64]) -------------
// lane = output column; W column lives in 64 VGPRs; rows broadcast.
// Optionally accumulates per-feature sum/sumsq (for BN) lane-locally.
#define ROWS_PER_WAVE 16
template <bool STATS>
__global__ __launch_bounds__(256) void gemm_kernel(const float* __restrict__ A,
                                                   const float* __restrict__ W,
                                                   const float* __restrict__ bias,
                                                   float* __restrict__ out,
                                                   float* __restrict__ stats, int N) {
  const int lane = threadIdx.x & 63;
  const int wid = threadIdx.x >> 6;

  float wreg[FD];
#pragma unroll
  for (int k = 0; k < FD; ++k) wreg[k] = W[k * FD + lane];
  const float bl = bias[lane];

  float s1 = 0.f, s2 = 0.f;
  const int row0 = (blockIdx.x * 4 + wid) * ROWS_PER_WAVE;
  for (int r = 0; r < ROWS_PER_WAVE; ++r) {
    const int row = row0 + r;
    if (row >= N) break;
    const float4* __restrict__ xr = (const float4*)(A + (size_t)row * FD);
    float acc = 0.f;
#pragma unroll
    for (int k4 = 0; k4 < FD / 4; ++k4) {
      float4 xv = xr[k4];
      acc = fmaf(xv.x, wreg[4 * k4 + 0], acc);
      acc = fmaf(xv.y, wreg[4 * k4 + 1], acc);
      acc = fmaf(xv.z, wreg[4 * k4 + 2], acc);
      acc = fmaf(xv.w, wreg[4 * k4 + 3], acc);
    }
    float o = acc + bl;
    out[(size_t)row * FD + lane] = o;
    if (STATS) {
      s1 += o;
      s2 += o * o;
    }
  }

  if (STATS) {
    __shared__ float ls1[256];
    __shared__ float ls2[256];
    ls1[threadIdx.x] = s1;
    ls2[threadIdx.x] = s2;
    __syncthreads();
    if (threadIdx.x < 64) {
      float a1 = ls1[threadIdx.x] + ls1[threadIdx.x + 64] + ls1[threadIdx.x + 128] +
                 ls1[threadIdx.x + 192];
      float a2 = ls2[threadIdx.x] + ls2[threadIdx.x + 64] + ls2[threadIdx.x + 128] +
                 ls2[threadIdx.x + 192];
      atomicAdd(&stats[threadIdx.x], a1);
      atomicAdd(&stats[64 + threadIdx.x], a2);
    }
  }
}

extern "C" void kernel_launch(void* const* d_in, const int* in_sizes, int n_in,
                              void* d_out, int out_size, void* d_ws, size_t ws_size,
                              hipStream_t stream) {
  const float* x = (const float*)d_in[0];
  const int* ei = (const int*)d_in[1];
  const float* W1 = (const float*)d_in[2];
  const float* b1 = (const float*)d_in[3];
  const float* g1 = (const float*)d_in[4];
  const float* be1 = (const float*)d_in[5];
  const float* W2 = (const float*)d_in[6];
  const float* b2 = (const float*)d_in[7];
  const float* g2 = (const float*)d_in[8];
  const float* be2 = (const float*)d_in[9];
  const float* W3 = (const float*)d_in[10];
  const float* b3 = (const float*)d_in[11];

  const int N = in_sizes[0] / FD;
  const int E = in_sizes[1] / 2;

  // ---- workspace carve-up (256B aligned) ----
  char* p = (char*)d_ws;
  auto alloc = [&](size_t bytes) {
    char* r = p;
    p += (bytes + 255) & ~(size_t)255;
    return r;
  };
  int* flag = (int*)alloc(4);
  float* stats1 = (float*)alloc(128 * 4);
  float* stats2 = (float*)alloc(128 * 4);
  int* partial = (int*)alloc(128 * 4);
  int* deg = (int*)alloc((size_t)N * 4);
  float* dinv = (float*)alloc((size_t)N * 4);
  int* rowptr = (int*)alloc((size_t)(N + 1) * 4);
  int* cursor = (int*)alloc((size_t)N * 4);
  int2* colw = (int2*)alloc((size_t)E * 8);
  float* bufA = (float*)alloc((size_t)N * FD * 4);
  float* bufB = (float*)alloc((size_t)N * FD * 4);
  (void)ws_size;

  hipMemsetAsync(deg, 0, (size_t)N * 4, stream);
  hipMemsetAsync(stats1, 0, 128 * 4, stream);
  hipMemsetAsync(stats2, 0, 128 * 4, stream);

  const int NB = (N + 1023) / 1024;  // 98 for N=100000, must be <= 128

  detect64_kernel<<<1, 64, 0, stream>>>(ei, flag);
  deg_kernel<<<(E + 255) / 256, 256, 0, stream>>>(ei, E, flag, deg);
  dinv_kernel<<<(N + 255) / 256, 256, 0, stream>>>(deg, dinv, N);
  scan1_kernel<<<NB, 1024, 0, stream>>>(deg, rowptr, partial, N);
  scan2_kernel<<<1, 128, 0, stream>>>(partial, NB);
  scan3_kernel<<<NB, 1024, 0, stream>>>(deg, rowptr, partial, cursor, N);
  fill_kernel<<<(E + 255) / 256, 256, 0, stream>>>(ei, E, flag, dinv, cursor, colw);

  const int aggGrid = (N + 3) / 4;
  const int gemmGrid = (N + 4 * ROWS_PER_WAVE - 1) / (4 * ROWS_PER_WAVE);

  // layer 1: agg(x) -> bufA ; bufA @ W1 + b1 -> bufB (+stats1)
  agg_kernel<false><<<aggGrid, 256, 0, stream>>>(x, rowptr, colw, dinv, nullptr, nullptr,
                                                 nullptr, bufA, N);
  gemm_kernel<true><<<gemmGrid, 256, 0, stream>>>(bufA, W1, b1, bufB, stats1, N);

  // layer 2: agg(relu(bn1(bufB))) -> bufA ; bufA @ W2 + b2 -> bufB (+stats2)
  agg_kernel<true><<<aggGrid, 256, 0, stream>>>(bufB, rowptr, colw, dinv, stats1, g1, be1,
                                                bufA, N);
  gemm_kernel<true><<<gemmGrid, 256, 0, stream>>>(bufA, W2, b2, bufB, stats2, N);

  // layer 3: agg(relu(bn2(bufB))) -> bufA ; bufA @ W3 + b3 -> d_out
  agg_kernel<true><<<aggGrid, 256, 0, stream>>>(bufB, rowptr, colw, dinv, stats2, g2, be2,
                                                bufA, N);
  gemm_kernel<false><<<gemmGrid, 256, 0, stream>>>(bufA, W3, b3, (float*)d_out, nullptr, N);
}

// Round 3
// 530.717 us; speedup vs baseline: 1.3028x; 1.0869x over previous
//
#include <hip/hip_runtime.h>
#include <hip/hip_bf16.h>

// GCN 3-layer fused pipeline for MI355X.
// Strategy: aggregate-then-transform ( Â(xW) == (Âx)W ), CSR built per call,
// BN+ReLU folded into the next gather as per-feature a*x+c.
// R3: (a) two-phase LDS-binned CSR fill (fixes 8x write-line amplification),
//     (b) bf16 gather table (halves agg gather traffic), GEMM emits bf16.

#define FD 64            // feature dim
#define EPSF 1e-5f

#define NBUCK 128        // dst-range buckets for two-phase fill
#define SLOTS 60         // LDS slots per bucket (128*60*8 = 60 KiB)
#define P1_EDGES 4096    // edges per phase-1 block

__device__ __forceinline__ float bf2f(ushort u) {
  return __uint_as_float((unsigned)u << 16);
}

// ---------------- edge width detection (int64 vs int32) ----------------
__global__ void detect64_kernel(const int* __restrict__ ei, int* __restrict__ flag) {
  int lane = threadIdx.x;
  int v = ei[2 * lane + 1];
  unsigned long long nz = __ballot(v != 0);
  if (lane == 0) *flag = (nz == 0ull) ? 1 : 0;
}

// ---------------- degree count ----------------
__global__ __launch_bounds__(256) void deg_kernel(const int* __restrict__ ei, int E,
                                                  const int* __restrict__ flag,
                                                  int* __restrict__ deg) {
  int e = blockIdx.x * 256 + threadIdx.x;
  if (e >= E) return;
  const int is64 = *flag;
  int d = is64 ? ei[2 * (E + e)] : ei[E + e];
  atomicAdd(&deg[d], 1);
}

// ---------------- dinv = rsqrt(deg + 1self) ----------------
__global__ __launch_bounds__(256) void dinv_kernel(const int* __restrict__ deg,
                                                   float* __restrict__ dinv, int N) {
  int i = blockIdx.x * 256 + threadIdx.x;
  if (i < N) dinv[i] = rsqrtf((float)(deg[i] + 1));
}

// ---------------- exclusive scan (3 kernels) ----------------
__global__ __launch_bounds__(1024) void scan1_kernel(const int* __restrict__ deg,
                                                     int* __restrict__ rowptr,
                                                     int* __restrict__ partial, int N) {
  __shared__ int lds[1024];
  int i = blockIdx.x * 1024 + threadIdx.x;
  int v = (i < N) ? deg[i] : 0;
  lds[threadIdx.x] = v;
  __syncthreads();
  for (int off = 1; off < 1024; off <<= 1) {
    int t = (threadIdx.x >= (unsigned)off) ? lds[threadIdx.x - off] : 0;
    __syncthreads();
    lds[threadIdx.x] += t;
    __syncthreads();
  }
  if (i < N) rowptr[i + 1] = lds[threadIdx.x];
  if (threadIdx.x == 1023) partial[blockIdx.x] = lds[1023];
}

__global__ __launch_bounds__(128) void scan2_kernel(int* __restrict__ partial, int B) {
  __shared__ int lds[128];
  int t = threadIdx.x;
  int v = (t < B) ? partial[t] : 0;
  lds[t] = v;
  __syncthreads();
  for (int off = 1; off < 128; off <<= 1) {
    int tv = (t >= off) ? lds[t - off] : 0;
    __syncthreads();
    lds[t] += tv;
    __syncthreads();
  }
  if (t < B) partial[t] = lds[t] - v;               // exclusive
}

__global__ __launch_bounds__(1024) void scan3_kernel(const int* __restrict__ deg,
                                                     int* __restrict__ rowptr,
                                                     const int* __restrict__ partial,
                                                     int* __restrict__ cursor, int N) {
  int i = blockIdx.x * 1024 + threadIdx.x;
  if (i < N) {
    int r = rowptr[i + 1] + partial[blockIdx.x];
    rowptr[i + 1] = r;
    cursor[i] = r - deg[i];                          // = final rowptr[i]
    if (i == 0) rowptr[0] = 0;
  }
}

// ---------------- bucket cursors = rowptr at bucket boundaries ----------------
__global__ void bbase_kernel(const int* __restrict__ rowptr, int* __restrict__ bcur,
                             int N, int NPB) {
  int b = threadIdx.x;
  if (b < NBUCK) bcur[b] = rowptr[min(b * NPB, N)];
}

// ---------------- phase-1 fill: LDS-binned staging (s, d) ----------------
__global__ __launch_bounds__(256) void fill1_kernel(const int* __restrict__ ei, int E,
                                                    const int* __restrict__ flag,
                                                    int* __restrict__ bcur,
                                                    int2* __restrict__ stage, int NPB) {
  __shared__ int2 sbuf[NBUCK][SLOTS];
  __shared__ int scnt[NBUCK];
  __shared__ int sbase[NBUCK];
  const int tid = threadIdx.x;
  for (int i = tid; i < NBUCK; i += 256) scnt[i] = 0;
  __syncthreads();
  const int is64 = *flag;
  const int base = blockIdx.x * P1_EDGES;
#pragma unroll 1
  for (int k = 0; k < P1_EDGES / 256; ++k) {
    int e = base + k * 256 + tid;
    if (e < E) {
      int s = is64 ? ei[2 * e] : ei[e];
      int d = is64 ? ei[2 * (E + e)] : ei[E + e];
      int b = d / NPB;
      int pos = atomicAdd(&scnt[b], 1);
      if (pos < SLOTS) {
        sbuf[b][pos] = make_int2(s, d);
      } else {
        stage[atomicAdd(&bcur[b], 1)] = make_int2(s, d);  // rare overflow
      }
    }
  }
  __syncthreads();
  for (int b = tid; b < NBUCK; b += 256) {
    int c = scnt[b];
    if (c > SLOTS) c = SLOTS;
    scnt[b] = c;
    sbase[b] = c ? atomicAdd(&bcur[b], c) : 0;
  }
  __syncthreads();
  for (int idx = tid; idx < NBUCK * SLOTS; idx += 256) {
    int b = idx / SLOTS, sl = idx - b * SLOTS;
    if (sl < scnt[b]) stage[sbase[b] + sl] = sbuf[b][sl];
  }
}

// ---------------- phase-2 fill: bucket-local scatter into exact CSR ----------------
__global__ __launch_bounds__(256) void fill2_kernel(const int2* __restrict__ stage,
                                                    const int* __restrict__ rowptr,
                                                    int* __restrict__ cursor,
                                                    const float* __restrict__ dinv,
                                                    int2* __restrict__ colw, int N,
                                                    int NPB) {
  const int b = blockIdx.x >> 1;
  const int half = blockIdx.x & 1;
  const int lo = rowptr[min(b * NPB, N)];
  const int hi = rowptr[min((b + 1) * NPB, N)];
  for (int i = lo + half * 256 + threadIdx.x; i < hi; i += 512) {
    int2 sd = stage[i];
    int slot = atomicAdd(&cursor[sd.y], 1);
    colw[slot] = make_int2(sd.x, __float_as_int(dinv[sd.x] * dinv[sd.y]));
  }
}

// ---------------- old direct fill (fallback if ws too small) ----------------
__global__ __launch_bounds__(256) void fill_direct_kernel(const int* __restrict__ ei, int E,
                                                          const int* __restrict__ flag,
                                                          const float* __restrict__ dinv,
                                                          int* __restrict__ cursor,
                                                          int2* __restrict__ colw) {
  int e = blockIdx.x * 256 + threadIdx.x;
  if (e >= E) return;
  const int is64 = *flag;
  int s = is64 ? ei[2 * e] : ei[e];
  int d = is64 ? ei[2 * (E + e)] : ei[E + e];
  int slot = atomicAdd(&cursor[d], 1);
  colw[slot] = make_int2(s, __float_as_int(dinv[s] * dinv[d]));
}

// ---------------- cast f32 -> bf16 table ----------------
__global__ __launch_bounds__(256) void cast_kernel(const float* __restrict__ in,
                                                   ushort* __restrict__ out, int total) {
  int i = (blockIdx.x * 256 + threadIdx.x) * 4;
  if (i >= total) return;
  float4 v = *(const float4*)(in + i);
  ushort4 o;
  { __hip_bfloat16 h = __float2bfloat16(v.x); o.x = *(ushort*)&h; }
  { __hip_bfloat16 h = __float2bfloat16(v.y); o.y = *(ushort*)&h; }
  { __hip_bfloat16 h = __float2bfloat16(v.z); o.z = *(ushort*)&h; }
  { __hip_bfloat16 h = __float2bfloat16(v.w); o.w = *(ushort*)&h; }
  *(ushort4*)(out + i) = o;
}

// ---------------- aggregation over bf16 table ----------------
// out[dst] = dinv[dst]^2 * f(H[dst]) + sum w * f(H[src]),  f = relu(a*x+c) if BN
template <bool BN>
__global__ __launch_bounds__(256) void agg_kernel(const ushort* __restrict__ H,
                                                  const int* __restrict__ rowptr,
                                                  const int2* __restrict__ colw,
                                                  const float* __restrict__ dinv,
                                                  const float* __restrict__ stats,  // [128]
                                                  const float* __restrict__ g,
                                                  const float* __restrict__ be,
                                                  float* __restrict__ out, int N) {
  const int lane = threadIdx.x & 63;
  const int wid = threadIdx.x >> 6;
  const int dst = blockIdx.x * 4 + wid;
  if (dst >= N) return;

  float a = 1.f, c = 0.f;
  if (BN) {
    float invN = 1.0f / (float)N;
    float m = stats[lane] * invN;
    float v = stats[64 + lane] * invN - m * m;
    float r = rsqrtf(v + EPSF);
    a = g[lane] * r;
    c = be[lane] - m * a;
  }

  const float di = dinv[dst];
  float hd = bf2f(H[dst * FD + lane]);
  if (BN) hd = fmaxf(fmaf(a, hd, c), 0.f);
  float acc0 = di * di * hd;
  float acc1 = 0.f, acc2 = 0.f, acc3 = 0.f;

  const int e0 = __builtin_amdgcn_readfirstlane(rowptr[dst]);
  const int e1 = __builtin_amdgcn_readfirstlane(rowptr[dst + 1]);
  int e = e0;
  for (; e + 3 < e1; e += 4) {
    int2 cw0 = colw[e];
    int2 cw1 = colw[e + 1];
    int2 cw2 = colw[e + 2];
    int2 cw3 = colw[e + 3];
    float h0 = bf2f(H[cw0.x * FD + lane]);
    float h1 = bf2f(H[cw1.x * FD + lane]);
    float h2 = bf2f(H[cw2.x * FD + lane]);
    float h3 = bf2f(H[cw3.x * FD + lane]);
    if (BN) {
      h0 = fmaxf(fmaf(a, h0, c), 0.f);
      h1 = fmaxf(fmaf(a, h1, c), 0.f);
      h2 = fmaxf(fmaf(a, h2, c), 0.f);
      h3 = fmaxf(fmaf(a, h3, c), 0.f);
    }
    acc0 = fmaf(__int_as_float(cw0.y), h0, acc0);
    acc1 = fmaf(__int_as_float(cw1.y), h1, acc1);
    acc2 = fmaf(__int_as_float(cw2.y), h2, acc2);
    acc3 = fmaf(__int_as_float(cw3.y), h3, acc3);
  }
  for (; e < e1; ++e) {
    int2 cw = colw[e];
    float h0 = bf2f(H[cw.x * FD + lane]);
    if (BN) h0 = fmaxf(fmaf(a, h0, c), 0.f);
    acc0 = fmaf(__int_as_float(cw.y), h0, acc0);
  }
  out[dst * FD + lane] = (acc0 + acc1) + (acc2 + acc3);
}

// ---------------- GEMM: out = A @ W + b  (A: [N,64] f32) ---------------------
// BF16OUT: write bf16 gather table + accumulate BN stats.
// else: write f32 (final layer -> d_out).
#define ROWS_PER_WAVE 16
template <bool BF16OUT>
__global__ __launch_bounds__(256) void gemm_kernel(const float* __restrict__ A,
                                                   const float* __restrict__ W,
                                                   const float* __restrict__ bias,
                                                   ushort* __restrict__ outb,
                                                   float* __restrict__ outf,
                                                   float* __restrict__ stats, int N) {
  const int lane = threadIdx.x & 63;
  const int wid = threadIdx.x >> 6;

  float wreg[FD];
#pragma unroll
  for (int k = 0; k < FD; ++k) wreg[k] = W[k * FD + lane];
  const float bl = bias[lane];

  float s1 = 0.f, s2 = 0.f;
  const int row0 = (blockIdx.x * 4 + wid) * ROWS_PER_WAVE;
  for (int r = 0; r < ROWS_PER_WAVE; ++r) {
    const int row = row0 + r;
    if (row >= N) break;
    const float4* __restrict__ xr = (const float4*)(A + (size_t)row * FD);
    float acc = 0.f;
#pragma unroll
    for (int k4 = 0; k4 < FD / 4; ++k4) {
      float4 xv = xr[k4];
      acc = fmaf(xv.x, wreg[4 * k4 + 0], acc);
      acc = fmaf(xv.y, wreg[4 * k4 + 1], acc);
      acc = fmaf(xv.z, wreg[4 * k4 + 2], acc);
      acc = fmaf(xv.w, wreg[4 * k4 + 3], acc);
    }
    float o = acc + bl;
    if (BF16OUT) {
      __hip_bfloat16 h = __float2bfloat16(o);
      outb[(size_t)row * FD + lane] = *(ushort*)&h;
      s1 += o;
      s2 += o * o;
    } else {
      outf[(size_t)row * FD + lane] = o;
    }
  }

  if (BF16OUT) {
    __shared__ float ls1[256];
    __shared__ float ls2[256];
    ls1[threadIdx.x] = s1;
    ls2[threadIdx.x] = s2;
    __syncthreads();
    if (threadIdx.x < 64) {
      float a1 = ls1[threadIdx.x] + ls1[threadIdx.x + 64] + ls1[threadIdx.x + 128] +
                 ls1[threadIdx.x + 192];
      float a2 = ls2[threadIdx.x] + ls2[threadIdx.x + 64] + ls2[threadIdx.x + 128] +
                 ls2[threadIdx.x + 192];
      atomicAdd(&stats[threadIdx.x], a1);
      atomicAdd(&stats[64 + threadIdx.x], a2);
    }
  }
}

extern "C" void kernel_launch(void* const* d_in, const int* in_sizes, int n_in,
                              void* d_out, int out_size, void* d_ws, size_t ws_size,
                              hipStream_t stream) {
  const float* x = (const float*)d_in[0];
  const int* ei = (const int*)d_in[1];
  const float* W1 = (const float*)d_in[2];
  const float* b1 = (const float*)d_in[3];
  const float* g1 = (const float*)d_in[4];
  const float* be1 = (const float*)d_in[5];
  const float* W2 = (const float*)d_in[6];
  const float* b2 = (const float*)d_in[7];
  const float* g2 = (const float*)d_in[8];
  const float* be2 = (const float*)d_in[9];
  const float* W3 = (const float*)d_in[10];
  const float* b3 = (const float*)d_in[11];

  const int N = in_sizes[0] / FD;
  const int E = in_sizes[1] / 2;
  const int NPB = (N + NBUCK - 1) / NBUCK;  // nodes per bucket

  // ---- workspace carve-up (256B aligned) ----
  char* p = (char*)d_ws;
  auto alloc = [&](size_t bytes) {
    char* r = p;
    p += (bytes + 255) & ~(size_t)255;
    return r;
  };
  int* flag = (int*)alloc(4);
  float* stats1 = (float*)alloc(128 * 4);
  float* stats2 = (float*)alloc(128 * 4);
  int* partial = (int*)alloc(128 * 4);
  int* bcur = (int*)alloc(NBUCK * 4);
  int* deg = (int*)alloc((size_t)N * 4);
  float* dinv = (float*)alloc((size_t)N * 4);
  int* rowptr = (int*)alloc((size_t)(N + 1) * 4);
  int* cursor = (int*)alloc((size_t)N * 4);
  int2* colw = (int2*)alloc((size_t)E * 8);
  float* bufA = (float*)alloc((size_t)N * FD * 4);     // agg out (f32 GEMM input)
  ushort* bufT = (ushort*)alloc((size_t)N * FD * 2);   // bf16 gather table
  size_t base_need = (size_t)(p - (char*)d_ws);
  int2* stage = (int2*)alloc((size_t)E * 8);           // two-phase staging
  size_t full_need = (size_t)(p - (char*)d_ws);
  const bool two_phase = (ws_size == 0) || (ws_size >= full_need);
  (void)base_need;

  hipMemsetAsync(deg, 0, (size_t)N * 4, stream);
  hipMemsetAsync(stats1, 0, 128 * 4, stream);
  hipMemsetAsync(stats2, 0, 128 * 4, stream);

  const int NB = (N + 1023) / 1024;  // 98 for N=100000, must be <= 128

  detect64_kernel<<<1, 64, 0, stream>>>(ei, flag);
  deg_kernel<<<(E + 255) / 256, 256, 0, stream>>>(ei, E, flag, deg);
  dinv_kernel<<<(N + 255) / 256, 256, 0, stream>>>(deg, dinv, N);
  scan1_kernel<<<NB, 1024, 0, stream>>>(deg, rowptr, partial, N);
  scan2_kernel<<<1, 128, 0, stream>>>(partial, NB);
  scan3_kernel<<<NB, 1024, 0, stream>>>(deg, rowptr, partial, cursor, N);

  if (two_phase) {
    bbase_kernel<<<1, NBUCK, 0, stream>>>(rowptr, bcur, N, NPB);
    fill1_kernel<<<(E + P1_EDGES - 1) / P1_EDGES, 256, 0, stream>>>(ei, E, flag, bcur,
                                                                    stage, NPB);
    fill2_kernel<<<2 * NBUCK, 256, 0, stream>>>(stage, rowptr, cursor, dinv, colw, N, NPB);
  } else {
    fill_direct_kernel<<<(E + 255) / 256, 256, 0, stream>>>(ei, E, flag, dinv, cursor,
                                                            colw);
  }

  const int aggGrid = (N + 3) / 4;
  const int gemmGrid = (N + 4 * ROWS_PER_WAVE - 1) / (4 * ROWS_PER_WAVE);
  const int castGrid = (N * FD / 4 + 255) / 256;

  // layer 1: cast(x) -> bufT ; agg(bufT) -> bufA ; bufA@W1+b1 -> bufT(bf16)+stats1
  cast_kernel<<<castGrid, 256, 0, stream>>>(x, bufT, N * FD);
  agg_kernel<false><<<aggGrid, 256, 0, stream>>>(bufT, rowptr, colw, dinv, nullptr,
                                                 nullptr, nullptr, bufA, N);
  gemm_kernel<true><<<gemmGrid, 256, 0, stream>>>(bufA, W1, b1, bufT, nullptr, stats1, N);

  // layer 2
  agg_kernel<true><<<aggGrid, 256, 0, stream>>>(bufT, rowptr, colw, dinv, stats1, g1, be1,
                                                bufA, N);
  gemm_kernel<true><<<gemmGrid, 256, 0, stream>>>(bufA, W2, b2, bufT, nullptr, stats2, N);

  // layer 3: final GEMM -> f32 d_out
  agg_kernel<true><<<aggGrid, 256, 0, stream>>>(bufT, rowptr, colw, dinv, stats2, g2, be2,
                                                bufA, N);
  gemm_kernel<false><<<gemmGrid, 256, 0, stream>>>(bufA, W3, b3, nullptr, (float*)d_out,
                                                   nullptr, N);
}

// Round 4
// 364.430 us; speedup vs baseline: 1.8972x; 1.4563x over previous
//
#include <hip/hip_runtime.h>
#include <hip/hip_bf16.h>

// GCN 3-layer fused pipeline for MI355X.
// Â(xW) == (Âx)W ; CSR built per call; BN+ReLU folded into next gather.
// R4: MFMA bf16 GEMM (16x16x32), agg emits bf16 directly (no f32 interbuf).

#define FD 64
#define EPSF 1e-5f

#define NBUCK 128
#define SLOTS 60
#define P1_EDGES 4096

typedef __attribute__((ext_vector_type(8))) short bf16x8;
typedef __attribute__((ext_vector_type(4))) float f32x4;

__device__ __forceinline__ float bf2f(ushort u) {
  return __uint_as_float((unsigned)u << 16);
}
__device__ __forceinline__ ushort f2bf_bits(float f) {
  __hip_bfloat16 h = __float2bfloat16(f);
  return *(ushort*)&h;
}

// ---------------- edge width detection (int64 vs int32) ----------------
__global__ void detect64_kernel(const int* __restrict__ ei, int* __restrict__ flag) {
  int lane = threadIdx.x;
  int v = ei[2 * lane + 1];
  unsigned long long nz = __ballot(v != 0);
  if (lane == 0) *flag = (nz == 0ull) ? 1 : 0;
}

// ---------------- degree count ----------------
__global__ __launch_bounds__(256) void deg_kernel(const int* __restrict__ ei, int E,
                                                  const int* __restrict__ flag,
                                                  int* __restrict__ deg) {
  int e = blockIdx.x * 256 + threadIdx.x;
  if (e >= E) return;
  const int is64 = *flag;
  int d = is64 ? ei[2 * (E + e)] : ei[E + e];
  atomicAdd(&deg[d], 1);
}

__global__ __launch_bounds__(256) void dinv_kernel(const int* __restrict__ deg,
                                                   float* __restrict__ dinv, int N) {
  int i = blockIdx.x * 256 + threadIdx.x;
  if (i < N) dinv[i] = rsqrtf((float)(deg[i] + 1));
}

// ---------------- exclusive scan (3 kernels) ----------------
__global__ __launch_bounds__(1024) void scan1_kernel(const int* __restrict__ deg,
                                                     int* __restrict__ rowptr,
                                                     int* __restrict__ partial, int N) {
  __shared__ int lds[1024];
  int i = blockIdx.x * 1024 + threadIdx.x;
  int v = (i < N) ? deg[i] : 0;
  lds[threadIdx.x] = v;
  __syncthreads();
  for (int off = 1; off < 1024; off <<= 1) {
    int t = (threadIdx.x >= (unsigned)off) ? lds[threadIdx.x - off] : 0;
    __syncthreads();
    lds[threadIdx.x] += t;
    __syncthreads();
  }
  if (i < N) rowptr[i + 1] = lds[threadIdx.x];
  if (threadIdx.x == 1023) partial[blockIdx.x] = lds[1023];
}

__global__ __launch_bounds__(128) void scan2_kernel(int* __restrict__ partial, int B) {
  __shared__ int lds[128];
  int t = threadIdx.x;
  int v = (t < B) ? partial[t] : 0;
  lds[t] = v;
  __syncthreads();
  for (int off = 1; off < 128; off <<= 1) {
    int tv = (t >= off) ? lds[t - off] : 0;
    __syncthreads();
    lds[t] += tv;
    __syncthreads();
  }
  if (t < B) partial[t] = lds[t] - v;               // exclusive
}

__global__ __launch_bounds__(1024) void scan3_kernel(const int* __restrict__ deg,
                                                     int* __restrict__ rowptr,
                                                     const int* __restrict__ partial,
                                                     int* __restrict__ cursor, int N) {
  int i = blockIdx.x * 1024 + threadIdx.x;
  if (i < N) {
    int r = rowptr[i + 1] + partial[blockIdx.x];
    rowptr[i + 1] = r;
    cursor[i] = r - deg[i];
    if (i == 0) rowptr[0] = 0;
  }
}

__global__ void bbase_kernel(const int* __restrict__ rowptr, int* __restrict__ bcur,
                             int N, int NPB) {
  int b = threadIdx.x;
  if (b < NBUCK) bcur[b] = rowptr[min(b * NPB, N)];
}

// ---------------- phase-1 fill: LDS-binned staging (s, d) ----------------
__global__ __launch_bounds__(256) void fill1_kernel(const int* __restrict__ ei, int E,
                                                    const int* __restrict__ flag,
                                                    int* __restrict__ bcur,
                                                    int2* __restrict__ stage, int NPB) {
  __shared__ int2 sbuf[NBUCK][SLOTS];
  __shared__ int scnt[NBUCK];
  __shared__ int sbase[NBUCK];
  const int tid = threadIdx.x;
  for (int i = tid; i < NBUCK; i += 256) scnt[i] = 0;
  __syncthreads();
  const int is64 = *flag;
  const int base = blockIdx.x * P1_EDGES;
#pragma unroll 1
  for (int k = 0; k < P1_EDGES / 256; ++k) {
    int e = base + k * 256 + tid;
    if (e < E) {
      int s = is64 ? ei[2 * e] : ei[e];
      int d = is64 ? ei[2 * (E + e)] : ei[E + e];
      int b = d / NPB;
      int pos = atomicAdd(&scnt[b], 1);
      if (pos < SLOTS) {
        sbuf[b][pos] = make_int2(s, d);
      } else {
        stage[atomicAdd(&bcur[b], 1)] = make_int2(s, d);
      }
    }
  }
  __syncthreads();
  for (int b = tid; b < NBUCK; b += 256) {
    int c = scnt[b];
    if (c > SLOTS) c = SLOTS;
    scnt[b] = c;
    sbase[b] = c ? atomicAdd(&bcur[b], c) : 0;
  }
  __syncthreads();
  for (int idx = tid; idx < NBUCK * SLOTS; idx += 256) {
    int b = idx / SLOTS, sl = idx - b * SLOTS;
    if (sl < scnt[b]) stage[sbase[b] + sl] = sbuf[b][sl];
  }
}

// ---------------- phase-2 fill: bucket-local scatter into exact CSR ----------------
__global__ __launch_bounds__(256) void fill2_kernel(const int2* __restrict__ stage,
                                                    const int* __restrict__ rowptr,
                                                    int* __restrict__ cursor,
                                                    const float* __restrict__ dinv,
                                                    int2* __restrict__ colw, int N,
                                                    int NPB) {
  const int b = blockIdx.x >> 1;
  const int half = blockIdx.x & 1;
  const int lo = rowptr[min(b * NPB, N)];
  const int hi = rowptr[min((b + 1) * NPB, N)];
  for (int i = lo + half * 256 + threadIdx.x; i < hi; i += 512) {
    int2 sd = stage[i];
    int slot = atomicAdd(&cursor[sd.y], 1);
    colw[slot] = make_int2(sd.x, __float_as_int(dinv[sd.x] * dinv[sd.y]));
  }
}

__global__ __launch_bounds__(256) void fill_direct_kernel(const int* __restrict__ ei, int E,
                                                          const int* __restrict__ flag,
                                                          const float* __restrict__ dinv,
                                                          int* __restrict__ cursor,
                                                          int2* __restrict__ colw) {
  int e = blockIdx.x * 256 + threadIdx.x;
  if (e >= E) return;
  const int is64 = *flag;
  int s = is64 ? ei[2 * e] : ei[e];
  int d = is64 ? ei[2 * (E + e)] : ei[E + e];
  int slot = atomicAdd(&cursor[d], 1);
  colw[slot] = make_int2(s, __float_as_int(dinv[s] * dinv[d]));
}

// ---------------- cast f32 -> bf16 table ----------------
__global__ __launch_bounds__(256) void cast_kernel(const float* __restrict__ in,
                                                   ushort* __restrict__ out, int total) {
  int i = (blockIdx.x * 256 + threadIdx.x) * 4;
  if (i >= total) return;
  float4 v = *(const float4*)(in + i);
  ushort4 o;
  o.x = f2bf_bits(v.x);
  o.y = f2bf_bits(v.y);
  o.z = f2bf_bits(v.z);
  o.w = f2bf_bits(v.w);
  *(ushort4*)(out + i) = o;
}

// ---------------- aggregation over bf16 table, bf16 out ----------------
template <bool BN>
__global__ __launch_bounds__(256) void agg_kernel(const ushort* __restrict__ H,
                                                  const int* __restrict__ rowptr,
                                                  const int2* __restrict__ colw,
                                                  const float* __restrict__ dinv,
                                                  const float* __restrict__ stats,
                                                  const float* __restrict__ g,
                                                  const float* __restrict__ be,
                                                  ushort* __restrict__ out, int N) {
  const int lane = threadIdx.x & 63;
  const int wid = threadIdx.x >> 6;
  const int dst = blockIdx.x * 4 + wid;
  if (dst >= N) return;

  float a = 1.f, c = 0.f;
  if (BN) {
    float invN = 1.0f / (float)N;
    float m = stats[lane] * invN;
    float v = stats[64 + lane] * invN - m * m;
    float r = rsqrtf(v + EPSF);
    a = g[lane] * r;
    c = be[lane] - m * a;
  }

  const float di = dinv[dst];
  float hd = bf2f(H[dst * FD + lane]);
  if (BN) hd = fmaxf(fmaf(a, hd, c), 0.f);
  float acc0 = di * di * hd;
  float acc1 = 0.f, acc2 = 0.f, acc3 = 0.f;

  const int e0 = __builtin_amdgcn_readfirstlane(rowptr[dst]);
  const int e1 = __builtin_amdgcn_readfirstlane(rowptr[dst + 1]);
  int e = e0;
  for (; e + 3 < e1; e += 4) {
    int2 cw0 = colw[e];
    int2 cw1 = colw[e + 1];
    int2 cw2 = colw[e + 2];
    int2 cw3 = colw[e + 3];
    float h0 = bf2f(H[cw0.x * FD + lane]);
    float h1 = bf2f(H[cw1.x * FD + lane]);
    float h2 = bf2f(H[cw2.x * FD + lane]);
    float h3 = bf2f(H[cw3.x * FD + lane]);
    if (BN) {
      h0 = fmaxf(fmaf(a, h0, c), 0.f);
      h1 = fmaxf(fmaf(a, h1, c), 0.f);
      h2 = fmaxf(fmaf(a, h2, c), 0.f);
      h3 = fmaxf(fmaf(a, h3, c), 0.f);
    }
    acc0 = fmaf(__int_as_float(cw0.y), h0, acc0);
    acc1 = fmaf(__int_as_float(cw1.y), h1, acc1);
    acc2 = fmaf(__int_as_float(cw2.y), h2, acc2);
    acc3 = fmaf(__int_as_float(cw3.y), h3, acc3);
  }
  for (; e < e1; ++e) {
    int2 cw = colw[e];
    float h0 = bf2f(H[cw.x * FD + lane]);
    if (BN) h0 = fmaxf(fmaf(a, h0, c), 0.f);
    acc0 = fmaf(__int_as_float(cw.y), h0, acc0);
  }
  out[dst * FD + lane] = f2bf_bits((acc0 + acc1) + (acc2 + acc3));
}

// ---------------- MFMA GEMM: out = A(bf16) @ W + b -------------------------
// Wave owns 16x64 tile. A-frag: m=lane&15, k=8*(lane>>4)+j (16B/lane load).
// B-frag (W): n=lane&15, k=8*(lane>>4)+j. D: col=lane&15, row=(lane>>4)*4+reg.
// BF16OUT: write bf16 table + BN stats; else f32 (final layer).
template <bool BF16OUT>
__global__ __launch_bounds__(256) void gemm_mfma_kernel(const ushort* __restrict__ A,
                                                        const float* __restrict__ W,
                                                        const float* __restrict__ bias,
                                                        ushort* __restrict__ outb,
                                                        float* __restrict__ outf,
                                                        float* __restrict__ stats, int N) {
  const int lane = threadIdx.x & 63;
  const int wid = threadIdx.x >> 6;
  const int lo = lane & 15;
  const int hi = lane >> 4;

  __shared__ float sred[128];
  if (BF16OUT) {
    if (threadIdx.x < 128) sred[threadIdx.x] = 0.f;
    __syncthreads();
  }

  // B fragments: bfrag[kk][nt], kk = K-half (0:k<32, 1:k>=32), nt = 16-col tile
  bf16x8 bfrag[2][4];
#pragma unroll
  for (int kk = 0; kk < 2; ++kk)
#pragma unroll
    for (int nt = 0; nt < 4; ++nt)
#pragma unroll
      for (int j = 0; j < 8; ++j) {
        int k = kk * 32 + hi * 8 + j;
        bfrag[kk][nt][j] = (short)f2bf_bits(W[k * FD + nt * 16 + lo]);
      }

  float bl[4];
#pragma unroll
  for (int nt = 0; nt < 4; ++nt) bl[nt] = bias[nt * 16 + lo];

  float s1[4] = {0.f, 0.f, 0.f, 0.f};
  float s2[4] = {0.f, 0.f, 0.f, 0.f};

  const int TILES = (N + 15) / 16;
  const int stride = gridDim.x * 4;
  for (int tile = blockIdx.x * 4 + wid; tile < TILES; tile += stride) {
    const int row0 = tile * 16;
    const int ar = min(row0 + lo, N - 1);
    const ushort* ap = A + (size_t)ar * FD + hi * 8;
    bf16x8 a0 = *(const bf16x8*)ap;
    bf16x8 a1 = *(const bf16x8*)(ap + 32);

    f32x4 acc[4] = {{0.f, 0.f, 0.f, 0.f},
                    {0.f, 0.f, 0.f, 0.f},
                    {0.f, 0.f, 0.f, 0.f},
                    {0.f, 0.f, 0.f, 0.f}};
#pragma unroll
    for (int nt = 0; nt < 4; ++nt) {
      acc[nt] = __builtin_amdgcn_mfma_f32_16x16x32_bf16(a0, bfrag[0][nt], acc[nt], 0, 0, 0);
      acc[nt] = __builtin_amdgcn_mfma_f32_16x16x32_bf16(a1, bfrag[1][nt], acc[nt], 0, 0, 0);
    }

#pragma unroll
    for (int nt = 0; nt < 4; ++nt) {
#pragma unroll
      for (int r = 0; r < 4; ++r) {
        int row = row0 + hi * 4 + r;
        if (row < N) {
          float o = acc[nt][r] + bl[nt];
          if (BF16OUT) {
            outb[(size_t)row * FD + nt * 16 + lo] = f2bf_bits(o);
            s1[nt] += o;
            s2[nt] += o * o;
          } else {
            outf[(size_t)row * FD + nt * 16 + lo] = o;
          }
        }
      }
    }
  }

  if (BF16OUT) {
#pragma unroll
    for (int nt = 0; nt < 4; ++nt) {
      atomicAdd(&sred[nt * 16 + lo], s1[nt]);
      atomicAdd(&sred[64 + nt * 16 + lo], s2[nt]);
    }
    __syncthreads();
    if (threadIdx.x < 128) atomicAdd(&stats[threadIdx.x], sred[threadIdx.x]);
  }
}

extern "C" void kernel_launch(void* const* d_in, const int* in_sizes, int n_in,
                              void* d_out, int out_size, void* d_ws, size_t ws_size,
                              hipStream_t stream) {
  const float* x = (const float*)d_in[0];
  const int* ei = (const int*)d_in[1];
  const float* W1 = (const float*)d_in[2];
  const float* b1 = (const float*)d_in[3];
  const float* g1 = (const float*)d_in[4];
  const float* be1 = (const float*)d_in[5];
  const float* W2 = (const float*)d_in[6];
  const float* b2 = (const float*)d_in[7];
  const float* g2 = (const float*)d_in[8];
  const float* be2 = (const float*)d_in[9];
  const float* W3 = (const float*)d_in[10];
  const float* b3 = (const float*)d_in[11];

  const int N = in_sizes[0] / FD;
  const int E = in_sizes[1] / 2;
  const int NPB = (N + NBUCK - 1) / NBUCK;

  char* p = (char*)d_ws;
  auto alloc = [&](size_t bytes) {
    char* r = p;
    p += (bytes + 255) & ~(size_t)255;
    return r;
  };
  int* flag = (int*)alloc(4);
  float* stats1 = (float*)alloc(128 * 4);
  float* stats2 = (float*)alloc(128 * 4);
  int* partial = (int*)alloc(128 * 4);
  int* bcur = (int*)alloc(NBUCK * 4);
  int* deg = (int*)alloc((size_t)N * 4);
  float* dinv = (float*)alloc((size_t)N * 4);
  int* rowptr = (int*)alloc((size_t)(N + 1) * 4);
  int* cursor = (int*)alloc((size_t)N * 4);
  int2* colw = (int2*)alloc((size_t)E * 8);
  ushort* T0 = (ushort*)alloc((size_t)N * FD * 2);
  ushort* T1 = (ushort*)alloc((size_t)N * FD * 2);
  size_t base_need = (size_t)(p - (char*)d_ws);
  int2* stage = (int2*)alloc((size_t)E * 8);
  size_t full_need = (size_t)(p - (char*)d_ws);
  const bool two_phase = (ws_size == 0) || (ws_size >= full_need);
  (void)base_need;

  hipMemsetAsync(deg, 0, (size_t)N * 4, stream);
  hipMemsetAsync(stats1, 0, 128 * 4, stream);
  hipMemsetAsync(stats2, 0, 128 * 4, stream);

  const int NB = (N + 1023) / 1024;

  detect64_kernel<<<1, 64, 0, stream>>>(ei, flag);
  deg_kernel<<<(E + 255) / 256, 256, 0, stream>>>(ei, E, flag, deg);
  dinv_kernel<<<(N + 255) / 256, 256, 0, stream>>>(deg, dinv, N);
  scan1_kernel<<<NB, 1024, 0, stream>>>(deg, rowptr, partial, N);
  scan2_kernel<<<1, 128, 0, stream>>>(partial, NB);
  scan3_kernel<<<NB, 1024, 0, stream>>>(deg, rowptr, partial, cursor, N);

  if (two_phase) {
    bbase_kernel<<<1, NBUCK, 0, stream>>>(rowptr, bcur, N, NPB);
    fill1_kernel<<<(E + P1_EDGES - 1) / P1_EDGES, 256, 0, stream>>>(ei, E, flag, bcur,
                                                                    stage, NPB);
    fill2_kernel<<<2 * NBUCK, 256, 0, stream>>>(stage, rowptr, cursor, dinv, colw, N, NPB);
  } else {
    fill_direct_kernel<<<(E + 255) / 256, 256, 0, stream>>>(ei, E, flag, dinv, cursor,
                                                            colw);
  }

  const int aggGrid = (N + 3) / 4;
  const int castGrid = (N * FD / 4 + 255) / 256;
  const int TILES = (N + 15) / 16;
  const int gemmGrid = (TILES + 15) / 16;  // 4 waves/block, ~4 tiles/wave

  // layer 1
  cast_kernel<<<castGrid, 256, 0, stream>>>(x, T0, N * FD);
  agg_kernel<false><<<aggGrid, 256, 0, stream>>>(T0, rowptr, colw, dinv, nullptr, nullptr,
                                                 nullptr, T1, N);
  gemm_mfma_kernel<true><<<gemmGrid, 256, 0, stream>>>(T1, W1, b1, T0, nullptr, stats1, N);

  // layer 2
  agg_kernel<true><<<aggGrid, 256, 0, stream>>>(T0, rowptr, colw, dinv, stats1, g1, be1,
                                                T1, N);
  gemm_mfma_kernel<true><<<gemmGrid, 256, 0, stream>>>(T1, W2, b2, T0, nullptr, stats2, N);

  // layer 3: final GEMM -> f32 d_out
  agg_kernel<true><<<aggGrid, 256, 0, stream>>>(T0, rowptr, colw, dinv, stats2, g2, be2,
                                                T1, N);
  gemm_mfma_kernel<false><<<gemmGrid, 256, 0, stream>>>(T1, W3, b3, nullptr,
                                                        (float*)d_out, nullptr, N);
}

// Round 5
// 351.377 us; speedup vs baseline: 1.9677x; 1.0371x over previous
//
#include <hip/hip_runtime.h>
#include <hip/hip_bf16.h>

// GCN 3-layer fused pipeline for MI355X.
// Â(xW) == (Âx)W ; CSR built per call; BN+ReLU folded into next gather.
// R5: degree via LDS-binned counting (no scattered global atomics),
//     agg 8-wide masked gather unroll.

#define FD 64
#define EPSF 1e-5f

#define NBUCK 256        // max buckets (bucket = dst >> BSHIFT)
#define BSHIFT 9
#define BWID 512         // nodes per bucket (pow2); supports N <= 131072
#define SLOTS 28         // LDS slots per bucket in fill1 (256*28*8 = 57 KiB)
#define P1_EDGES 4096

typedef __attribute__((ext_vector_type(8))) short bf16x8;
typedef __attribute__((ext_vector_type(4))) float f32x4;

__device__ __forceinline__ float bf2f(ushort u) {
  return __uint_as_float((unsigned)u << 16);
}
__device__ __forceinline__ ushort f2bf_bits(float f) {
  __hip_bfloat16 h = __float2bfloat16(f);
  return *(ushort*)&h;
}

// ---------------- edge width detection (int64 vs int32) ----------------
__global__ void detect64_kernel(const int* __restrict__ ei, int* __restrict__ flag) {
  int lane = threadIdx.x;
  int v = ei[2 * lane + 1];
  unsigned long long nz = __ballot(v != 0);
  if (lane == 0) *flag = (nz == 0ull) ? 1 : 0;
}

// ---------------- bucket histogram of dst ----------------
__global__ __launch_bounds__(256) void hist_kernel(const int* __restrict__ ei, int E,
                                                   const int* __restrict__ flag,
                                                   int* __restrict__ bhist) {
  __shared__ int h[NBUCK];
  const int tid = threadIdx.x;
  h[tid] = 0;
  __syncthreads();
  const int is64 = *flag;
  const int base = blockIdx.x * P1_EDGES;
#pragma unroll 1
  for (int k = 0; k < P1_EDGES / 256; ++k) {
    int e = base + k * 256 + tid;
    if (e < E) {
      int d = is64 ? ei[2 * (E + e)] : ei[E + e];
      atomicAdd(&h[d >> BSHIFT], 1);
    }
  }
  __syncthreads();
  if (h[tid]) atomicAdd(&bhist[tid], h[tid]);
}

// ---------------- exclusive scan of 256 bucket counts -> stage bases ----------
__global__ __launch_bounds__(256) void bscan_kernel(const int* __restrict__ bhist,
                                                    int* __restrict__ bbase,
                                                    int* __restrict__ bcur) {
  __shared__ int lds[NBUCK];
  int t = threadIdx.x;
  int v = bhist[t];
  lds[t] = v;
  __syncthreads();
  for (int off = 1; off < NBUCK; off <<= 1) {
    int tv = (t >= off) ? lds[t - off] : 0;
    __syncthreads();
    lds[t] += tv;
    __syncthreads();
  }
  int ex = lds[t] - v;  // exclusive
  bbase[t] = ex;
  bcur[t] = ex;
}

// ---------------- phase-1 fill: LDS-binned staging (s, d) ----------------
__global__ __launch_bounds__(256) void fill1_kernel(const int* __restrict__ ei, int E,
                                                    const int* __restrict__ flag,
                                                    int* __restrict__ bcur,
                                                    int2* __restrict__ stage) {
  __shared__ int2 sbuf[NBUCK][SLOTS];
  __shared__ int scnt[NBUCK];
  __shared__ int sbase[NBUCK];
  const int tid = threadIdx.x;
  scnt[tid] = 0;
  __syncthreads();
  const int is64 = *flag;
  const int base = blockIdx.x * P1_EDGES;
#pragma unroll 1
  for (int k = 0; k < P1_EDGES / 256; ++k) {
    int e = base + k * 256 + tid;
    if (e < E) {
      int s = is64 ? ei[2 * e] : ei[e];
      int d = is64 ? ei[2 * (E + e)] : ei[E + e];
      int b = d >> BSHIFT;
      int pos = atomicAdd(&scnt[b], 1);
      if (pos < SLOTS) {
        sbuf[b][pos] = make_int2(s, d);
      } else {
        stage[atomicAdd(&bcur[b], 1)] = make_int2(s, d);  // rare overflow
      }
    }
  }
  __syncthreads();
  {
    int c = scnt[tid];
    if (c > SLOTS) c = SLOTS;
    scnt[tid] = c;
    sbase[tid] = c ? atomicAdd(&bcur[tid], c) : 0;
  }
  __syncthreads();
  for (int idx = tid; idx < NBUCK * SLOTS; idx += 256) {
    int b = idx / SLOTS, sl = idx - b * SLOTS;
    if (sl < scnt[b]) stage[sbase[b] + sl] = sbuf[b][sl];
  }
}

// ---------------- per-bucket degree count (LDS hist) + dinv ----------------
__global__ __launch_bounds__(256) void degcount_kernel(const int2* __restrict__ stage,
                                                       const int* __restrict__ bbase,
                                                       const int* __restrict__ bcur,
                                                       int* __restrict__ deg,
                                                       float* __restrict__ dinv, int N) {
  __shared__ int h[BWID];
  const int b = blockIdx.x;
  const int tid = threadIdx.x;
  for (int i = tid; i < BWID; i += 256) h[i] = 0;
  __syncthreads();
  const int lo = bbase[b], hi = bcur[b];
  for (int i = lo + tid; i < hi; i += 256)
    atomicAdd(&h[stage[i].y - (b << BSHIFT)], 1);
  __syncthreads();
  const int n0 = b << BSHIFT;
  for (int i = tid; i < BWID; i += 256) {
    int node = n0 + i;
    if (node < N) {
      int d = h[i];
      deg[node] = d;
      dinv[node] = rsqrtf((float)(d + 1));
    }
  }
}

// ---------------- exclusive scan (3 kernels) ----------------
__global__ __launch_bounds__(1024) void scan1_kernel(const int* __restrict__ deg,
                                                     int* __restrict__ rowptr,
                                                     int* __restrict__ partial, int N) {
  __shared__ int lds[1024];
  int i = blockIdx.x * 1024 + threadIdx.x;
  int v = (i < N) ? deg[i] : 0;
  lds[threadIdx.x] = v;
  __syncthreads();
  for (int off = 1; off < 1024; off <<= 1) {
    int t = (threadIdx.x >= (unsigned)off) ? lds[threadIdx.x - off] : 0;
    __syncthreads();
    lds[threadIdx.x] += t;
    __syncthreads();
  }
  if (i < N) rowptr[i + 1] = lds[threadIdx.x];
  if (threadIdx.x == 1023) partial[blockIdx.x] = lds[1023];
}

__global__ __launch_bounds__(128) void scan2_kernel(int* __restrict__ partial, int B) {
  __shared__ int lds[128];
  int t = threadIdx.x;
  int v = (t < B) ? partial[t] : 0;
  lds[t] = v;
  __syncthreads();
  for (int off = 1; off < 128; off <<= 1) {
    int tv = (t >= off) ? lds[t - off] : 0;
    __syncthreads();
    lds[t] += tv;
    __syncthreads();
  }
  if (t < B) partial[t] = lds[t] - v;               // exclusive
}

__global__ __launch_bounds__(1024) void scan3_kernel(const int* __restrict__ deg,
                                                     int* __restrict__ rowptr,
                                                     const int* __restrict__ partial,
                                                     int* __restrict__ cursor, int N) {
  int i = blockIdx.x * 1024 + threadIdx.x;
  if (i < N) {
    int r = rowptr[i + 1] + partial[blockIdx.x];
    rowptr[i + 1] = r;
    cursor[i] = r - deg[i];
    if (i == 0) rowptr[0] = 0;
  }
}

// ---------------- phase-2 fill: bucket-local scatter into exact CSR ----------------
__global__ __launch_bounds__(256) void fill2_kernel(const int2* __restrict__ stage,
                                                    const int* __restrict__ bbase,
                                                    const int* __restrict__ bcur,
                                                    int* __restrict__ cursor,
                                                    const float* __restrict__ dinv,
                                                    int2* __restrict__ colw) {
  const int b = blockIdx.x >> 1;
  const int half = blockIdx.x & 1;
  const int lo = bbase[b];
  const int hi = bcur[b];
  for (int i = lo + half * 256 + threadIdx.x; i < hi; i += 512) {
    int2 sd = stage[i];
    int slot = atomicAdd(&cursor[sd.y], 1);
    colw[slot] = make_int2(sd.x, __float_as_int(dinv[sd.x] * dinv[sd.y]));
  }
}

// ---------------- fallback path (small ws): direct atomics ----------------
__global__ __launch_bounds__(256) void deg_atomic_kernel(const int* __restrict__ ei, int E,
                                                         const int* __restrict__ flag,
                                                         int* __restrict__ deg) {
  int e = blockIdx.x * 256 + threadIdx.x;
  if (e >= E) return;
  const int is64 = *flag;
  int d = is64 ? ei[2 * (E + e)] : ei[E + e];
  atomicAdd(&deg[d], 1);
}
__global__ __launch_bounds__(256) void dinv_kernel(const int* __restrict__ deg,
                                                   float* __restrict__ dinv, int N) {
  int i = blockIdx.x * 256 + threadIdx.x;
  if (i < N) dinv[i] = rsqrtf((float)(deg[i] + 1));
}
__global__ __launch_bounds__(256) void fill_direct_kernel(const int* __restrict__ ei, int E,
                                                          const int* __restrict__ flag,
                                                          const float* __restrict__ dinv,
                                                          int* __restrict__ cursor,
                                                          int2* __restrict__ colw) {
  int e = blockIdx.x * 256 + threadIdx.x;
  if (e >= E) return;
  const int is64 = *flag;
  int s = is64 ? ei[2 * e] : ei[e];
  int d = is64 ? ei[2 * (E + e)] : ei[E + e];
  int slot = atomicAdd(&cursor[d], 1);
  colw[slot] = make_int2(s, __float_as_int(dinv[s] * dinv[d]));
}

// ---------------- cast f32 -> bf16 table ----------------
__global__ __launch_bounds__(256) void cast_kernel(const float* __restrict__ in,
                                                   ushort* __restrict__ out, int total) {
  int i = (blockIdx.x * 256 + threadIdx.x) * 4;
  if (i >= total) return;
  float4 v = *(const float4*)(in + i);
  ushort4 o;
  o.x = f2bf_bits(v.x);
  o.y = f2bf_bits(v.y);
  o.z = f2bf_bits(v.z);
  o.w = f2bf_bits(v.w);
  *(ushort4*)(out + i) = o;
}

// ---------------- aggregation over bf16 table, bf16 out ----------------
// out[dst] = dinv^2 * f(H[dst]) + sum w * f(H[src]); f = relu(a*x+c) if BN.
// 8-wide masked unroll: 8 independent gather chains per wave.
template <bool BN>
__global__ __launch_bounds__(256) void agg_kernel(const ushort* __restrict__ H,
                                                  const int* __restrict__ rowptr,
                                                  const int2* __restrict__ colw,
                                                  const float* __restrict__ dinv,
                                                  const float* __restrict__ stats,
                                                  const float* __restrict__ g,
                                                  const float* __restrict__ be,
                                                  ushort* __restrict__ out, int N) {
  const int lane = threadIdx.x & 63;
  const int wid = threadIdx.x >> 6;
  const int dst = blockIdx.x * 4 + wid;
  if (dst >= N) return;

  float a = 1.f, c = 0.f;
  if (BN) {
    float invN = 1.0f / (float)N;
    float m = stats[lane] * invN;
    float v = stats[64 + lane] * invN - m * m;
    float r = rsqrtf(v + EPSF);
    a = g[lane] * r;
    c = be[lane] - m * a;
  }

  const float di = dinv[dst];
  float hd = bf2f(H[(size_t)dst * FD + lane]);
  if (BN) hd = fmaxf(fmaf(a, hd, c), 0.f);
  const float self = di * di * hd;

  float acc[8] = {0.f, 0.f, 0.f, 0.f, 0.f, 0.f, 0.f, 0.f};

  const int e0 = __builtin_amdgcn_readfirstlane(rowptr[dst]);
  const int e1 = __builtin_amdgcn_readfirstlane(rowptr[dst + 1]);
  for (int e = e0; e < e1; e += 8) {
#pragma unroll
    for (int u = 0; u < 8; ++u) {
      int ee = e + u;
      int idx = (ee < e1) ? ee : (e1 - 1);
      int2 cw = colw[idx];
      float w = (ee < e1) ? __int_as_float(cw.y) : 0.f;
      float h = bf2f(H[(size_t)cw.x * FD + lane]);
      if (BN) h = fmaxf(fmaf(a, h, c), 0.f);
      acc[u] = fmaf(w, h, acc[u]);
    }
  }
  float s = ((acc[0] + acc[1]) + (acc[2] + acc[3])) +
            ((acc[4] + acc[5]) + (acc[6] + acc[7])) + self;
  out[(size_t)dst * FD + lane] = f2bf_bits(s);
}

// ---------------- MFMA GEMM: out = A(bf16) @ W + b -------------------------
template <bool BF16OUT>
__global__ __launch_bounds__(256) void gemm_mfma_kernel(const ushort* __restrict__ A,
                                                        const float* __restrict__ W,
                                                        const float* __restrict__ bias,
                                                        ushort* __restrict__ outb,
                                                        float* __restrict__ outf,
                                                        float* __restrict__ stats, int N) {
  const int lane = threadIdx.x & 63;
  const int wid = threadIdx.x >> 6;
  const int lo = lane & 15;
  const int hi = lane >> 4;

  __shared__ float sred[128];
  if (BF16OUT) {
    if (threadIdx.x < 128) sred[threadIdx.x] = 0.f;
    __syncthreads();
  }

  bf16x8 bfrag[2][4];
#pragma unroll
  for (int kk = 0; kk < 2; ++kk)
#pragma unroll
    for (int nt = 0; nt < 4; ++nt)
#pragma unroll
      for (int j = 0; j < 8; ++j) {
        int k = kk * 32 + hi * 8 + j;
        bfrag[kk][nt][j] = (short)f2bf_bits(W[k * FD + nt * 16 + lo]);
      }

  float bl[4];
#pragma unroll
  for (int nt = 0; nt < 4; ++nt) bl[nt] = bias[nt * 16 + lo];

  float s1[4] = {0.f, 0.f, 0.f, 0.f};
  float s2[4] = {0.f, 0.f, 0.f, 0.f};

  const int TILES = (N + 15) / 16;
  const int stride = gridDim.x * 4;
  for (int tile = blockIdx.x * 4 + wid; tile < TILES; tile += stride) {
    const int row0 = tile * 16;
    const int ar = min(row0 + lo, N - 1);
    const ushort* ap = A + (size_t)ar * FD + hi * 8;
    bf16x8 a0 = *(const bf16x8*)ap;
    bf16x8 a1 = *(const bf16x8*)(ap + 32);

    f32x4 acc[4] = {{0.f, 0.f, 0.f, 0.f},
                    {0.f, 0.f, 0.f, 0.f},
                    {0.f, 0.f, 0.f, 0.f},
                    {0.f, 0.f, 0.f, 0.f}};
#pragma unroll
    for (int nt = 0; nt < 4; ++nt) {
      acc[nt] = __builtin_amdgcn_mfma_f32_16x16x32_bf16(a0, bfrag[0][nt], acc[nt], 0, 0, 0);
      acc[nt] = __builtin_amdgcn_mfma_f32_16x16x32_bf16(a1, bfrag[1][nt], acc[nt], 0, 0, 0);
    }

#pragma unroll
    for (int nt = 0; nt < 4; ++nt) {
#pragma unroll
      for (int r = 0; r < 4; ++r) {
        int row = row0 + hi * 4 + r;
        if (row < N) {
          float o = acc[nt][r] + bl[nt];
          if (BF16OUT) {
            outb[(size_t)row * FD + nt * 16 + lo] = f2bf_bits(o);
            s1[nt] += o;
            s2[nt] += o * o;
          } else {
            outf[(size_t)row * FD + nt * 16 + lo] = o;
          }
        }
      }
    }
  }

  if (BF16OUT) {
#pragma unroll
    for (int nt = 0; nt < 4; ++nt) {
      atomicAdd(&sred[nt * 16 + lo], s1[nt]);
      atomicAdd(&sred[64 + nt * 16 + lo], s2[nt]);
    }
    __syncthreads();
    if (threadIdx.x < 128) atomicAdd(&stats[threadIdx.x], sred[threadIdx.x]);
  }
}

extern "C" void kernel_launch(void* const* d_in, const int* in_sizes, int n_in,
                              void* d_out, int out_size, void* d_ws, size_t ws_size,
                              hipStream_t stream) {
  const float* x = (const float*)d_in[0];
  const int* ei = (const int*)d_in[1];
  const float* W1 = (const float*)d_in[2];
  const float* b1 = (const float*)d_in[3];
  const float* g1 = (const float*)d_in[4];
  const float* be1 = (const float*)d_in[5];
  const float* W2 = (const float*)d_in[6];
  const float* b2 = (const float*)d_in[7];
  const float* g2 = (const float*)d_in[8];
  const float* be2 = (const float*)d_in[9];
  const float* W3 = (const float*)d_in[10];
  const float* b3 = (const float*)d_in[11];

  const int N = in_sizes[0] / FD;
  const int E = in_sizes[1] / 2;
  const int nB = (N + BWID - 1) >> BSHIFT;  // used buckets

  char* p = (char*)d_ws;
  auto alloc = [&](size_t bytes) {
    char* r = p;
    p += (bytes + 255) & ~(size_t)255;
    return r;
  };
  int* flag = (int*)alloc(4);
  float* stats1 = (float*)alloc(128 * 4);
  float* stats2 = (float*)alloc(128 * 4);
  int* partial = (int*)alloc(128 * 4);
  int* bhist = (int*)alloc(NBUCK * 4);
  int* bbase = (int*)alloc(NBUCK * 4);
  int* bcur = (int*)alloc(NBUCK * 4);
  int* deg = (int*)alloc((size_t)N * 4);
  float* dinv = (float*)alloc((size_t)N * 4);
  int* rowptr = (int*)alloc((size_t)(N + 1) * 4);
  int* cursor = (int*)alloc((size_t)N * 4);
  int2* colw = (int2*)alloc((size_t)E * 8);
  ushort* T0 = (ushort*)alloc((size_t)N * FD * 2);
  ushort* T1 = (ushort*)alloc((size_t)N * FD * 2);
  size_t base_need = (size_t)(p - (char*)d_ws);
  int2* stage = (int2*)alloc((size_t)E * 8);
  size_t full_need = (size_t)(p - (char*)d_ws);
  const bool two_phase =
      ((ws_size == 0) || (ws_size >= full_need)) && (N <= NBUCK * BWID);
  (void)base_need;

  hipMemsetAsync(stats1, 0, 128 * 4, stream);
  hipMemsetAsync(stats2, 0, 128 * 4, stream);

  const int NB = (N + 1023) / 1024;
  const int EB = (E + P1_EDGES - 1) / P1_EDGES;

  detect64_kernel<<<1, 64, 0, stream>>>(ei, flag);

  if (two_phase) {
    hipMemsetAsync(bhist, 0, NBUCK * 4, stream);
    hist_kernel<<<EB, 256, 0, stream>>>(ei, E, flag, bhist);
    bscan_kernel<<<1, NBUCK, 0, stream>>>(bhist, bbase, bcur);
    fill1_kernel<<<EB, 256, 0, stream>>>(ei, E, flag, bcur, stage);
    degcount_kernel<<<nB, 256, 0, stream>>>(stage, bbase, bcur, deg, dinv, N);
    scan1_kernel<<<NB, 1024, 0, stream>>>(deg, rowptr, partial, N);
    scan2_kernel<<<1, 128, 0, stream>>>(partial, NB);
    scan3_kernel<<<NB, 1024, 0, stream>>>(deg, rowptr, partial, cursor, N);
    fill2_kernel<<<2 * nB, 256, 0, stream>>>(stage, bbase, bcur, cursor, dinv, colw);
  } else {
    hipMemsetAsync(deg, 0, (size_t)N * 4, stream);
    deg_atomic_kernel<<<(E + 255) / 256, 256, 0, stream>>>(ei, E, flag, deg);
    dinv_kernel<<<(N + 255) / 256, 256, 0, stream>>>(deg, dinv, N);
    scan1_kernel<<<NB, 1024, 0, stream>>>(deg, rowptr, partial, N);
    scan2_kernel<<<1, 128, 0, stream>>>(partial, NB);
    scan3_kernel<<<NB, 1024, 0, stream>>>(deg, rowptr, partial, cursor, N);
    fill_direct_kernel<<<(E + 255) / 256, 256, 0, stream>>>(ei, E, flag, dinv, cursor,
                                                            colw);
  }

  const int aggGrid = (N + 3) / 4;
  const int castGrid = (N * FD / 4 + 255) / 256;
  const int TILES = (N + 15) / 16;
  const int gemmGrid = (TILES + 15) / 16;

  // layer 1
  cast_kernel<<<castGrid, 256, 0, stream>>>(x, T0, N * FD);
  agg_kernel<false><<<aggGrid, 256, 0, stream>>>(T0, rowptr, colw, dinv, nullptr, nullptr,
                                                 nullptr, T1, N);
  gemm_mfma_kernel<true><<<gemmGrid, 256, 0, stream>>>(T1, W1, b1, T0, nullptr, stats1, N);

  // layer 2
  agg_kernel<true><<<aggGrid, 256, 0, stream>>>(T0, rowptr, colw, dinv, stats1, g1, be1,
                                                T1, N);
  gemm_mfma_kernel<true><<<gemmGrid, 256, 0, stream>>>(T1, W2, b2, T0, nullptr, stats2, N);

  // layer 3: final GEMM -> f32 d_out
  agg_kernel<true><<<aggGrid, 256, 0, stream>>>(T0, rowptr, colw, dinv, stats2, g2, be2,
                                                T1, N);
  gemm_mfma_kernel<false><<<gemmGrid, 256, 0, stream>>>(T1, W3, b3, nullptr,
                                                        (float*)d_out, nullptr, N);
}

// Round 6
// 317.261 us; speedup vs baseline: 2.1793x; 1.1075x over previous
//
#include <hip/hip_runtime.h>
#include <hip/hip_bf16.h>

// GCN 3-layer fused pipeline for MI355X.
// Â(xW) == (Âx)W ; CSR built per call; BN+ReLU folded into next gather.
// R6: agg repacked as 4 dst per wave (16-lane groups, ushort4/lane) ->
//     4 edges per wave instruction; init fusion (detect+zeroing).

#define FD 64
#define EPSF 1e-5f

#define NBUCK 256        // max buckets (bucket = dst >> BSHIFT)
#define BSHIFT 9
#define BWID 512         // nodes per bucket (pow2); supports N <= 131072
#define SLOTS 28         // LDS slots per bucket in fill1 (256*28*8 = 57 KiB)
#define P1_EDGES 4096

typedef __attribute__((ext_vector_type(8))) short bf16x8;
typedef __attribute__((ext_vector_type(4))) float f32x4;

__device__ __forceinline__ float bf2f(ushort u) {
  return __uint_as_float((unsigned)u << 16);
}
__device__ __forceinline__ ushort f2bf_bits(float f) {
  __hip_bfloat16 h = __float2bfloat16(f);
  return *(ushort*)&h;
}

// ---------------- init: edge-width detect + zero bhist/stats ----------------
__global__ __launch_bounds__(256) void init_kernel(const int* __restrict__ ei,
                                                   int* __restrict__ flag,
                                                   int* __restrict__ bhist,
                                                   float* __restrict__ stats1,
                                                   float* __restrict__ stats2) {
  int t = threadIdx.x;
  bhist[t] = 0;
  if (t < 128) {
    stats1[t] = 0.f;
    stats2[t] = 0.f;
  }
  if (t < 64) {
    int v = ei[2 * t + 1];
    unsigned long long nz = __ballot(v != 0);
    if (t == 0) *flag = (nz == 0ull) ? 1 : 0;
  }
}

// ---------------- bucket histogram of dst ----------------
__global__ __launch_bounds__(256) void hist_kernel(const int* __restrict__ ei, int E,
                                                   const int* __restrict__ flag,
                                                   int* __restrict__ bhist) {
  __shared__ int h[NBUCK];
  const int tid = threadIdx.x;
  h[tid] = 0;
  __syncthreads();
  const int is64 = *flag;
  const int base = blockIdx.x * P1_EDGES;
#pragma unroll 1
  for (int k = 0; k < P1_EDGES / 256; ++k) {
    int e = base + k * 256 + tid;
    if (e < E) {
      int d = is64 ? ei[2 * (E + e)] : ei[E + e];
      atomicAdd(&h[d >> BSHIFT], 1);
    }
  }
  __syncthreads();
  if (h[tid]) atomicAdd(&bhist[tid], h[tid]);
}

// ---------------- exclusive scan of 256 bucket counts -> stage bases ----------
__global__ __launch_bounds__(256) void bscan_kernel(const int* __restrict__ bhist,
                                                    int* __restrict__ bbase,
                                                    int* __restrict__ bcur) {
  __shared__ int lds[NBUCK];
  int t = threadIdx.x;
  int v = bhist[t];
  lds[t] = v;
  __syncthreads();
  for (int off = 1; off < NBUCK; off <<= 1) {
    int tv = (t >= off) ? lds[t - off] : 0;
    __syncthreads();
    lds[t] += tv;
    __syncthreads();
  }
  int ex = lds[t] - v;  // exclusive
  bbase[t] = ex;
  bcur[t] = ex;
}

// ---------------- phase-1 fill: LDS-binned staging (s, d) ----------------
__global__ __launch_bounds__(256) void fill1_kernel(const int* __restrict__ ei, int E,
                                                    const int* __restrict__ flag,
                                                    int* __restrict__ bcur,
                                                    int2* __restrict__ stage) {
  __shared__ int2 sbuf[NBUCK][SLOTS];
  __shared__ int scnt[NBUCK];
  __shared__ int sbase[NBUCK];
  const int tid = threadIdx.x;
  scnt[tid] = 0;
  __syncthreads();
  const int is64 = *flag;
  const int base = blockIdx.x * P1_EDGES;
#pragma unroll 1
  for (int k = 0; k < P1_EDGES / 256; ++k) {
    int e = base + k * 256 + tid;
    if (e < E) {
      int s = is64 ? ei[2 * e] : ei[e];
      int d = is64 ? ei[2 * (E + e)] : ei[E + e];
      int b = d >> BSHIFT;
      int pos = atomicAdd(&scnt[b], 1);
      if (pos < SLOTS) {
        sbuf[b][pos] = make_int2(s, d);
      } else {
        stage[atomicAdd(&bcur[b], 1)] = make_int2(s, d);  // rare overflow
      }
    }
  }
  __syncthreads();
  {
    int c = scnt[tid];
    if (c > SLOTS) c = SLOTS;
    scnt[tid] = c;
    sbase[tid] = c ? atomicAdd(&bcur[tid], c) : 0;
  }
  __syncthreads();
  for (int idx = tid; idx < NBUCK * SLOTS; idx += 256) {
    int b = idx / SLOTS, sl = idx - b * SLOTS;
    if (sl < scnt[b]) stage[sbase[b] + sl] = sbuf[b][sl];
  }
}

// ---------------- per-bucket degree count (LDS hist) + dinv ----------------
__global__ __launch_bounds__(256) void degcount_kernel(const int2* __restrict__ stage,
                                                       const int* __restrict__ bbase,
                                                       const int* __restrict__ bcur,
                                                       int* __restrict__ deg,
                                                       float* __restrict__ dinv, int N) {
  __shared__ int h[BWID];
  const int b = blockIdx.x;
  const int tid = threadIdx.x;
  for (int i = tid; i < BWID; i += 256) h[i] = 0;
  __syncthreads();
  const int lo = bbase[b], hi = bcur[b];
  for (int i = lo + tid; i < hi; i += 256)
    atomicAdd(&h[stage[i].y - (b << BSHIFT)], 1);
  __syncthreads();
  const int n0 = b << BSHIFT;
  for (int i = tid; i < BWID; i += 256) {
    int node = n0 + i;
    if (node < N) {
      int d = h[i];
      deg[node] = d;
      dinv[node] = rsqrtf((float)(d + 1));
    }
  }
}

// ---------------- exclusive scan (3 kernels) ----------------
__global__ __launch_bounds__(1024) void scan1_kernel(const int* __restrict__ deg,
                                                     int* __restrict__ rowptr,
                                                     int* __restrict__ partial, int N) {
  __shared__ int lds[1024];
  int i = blockIdx.x * 1024 + threadIdx.x;
  int v = (i < N) ? deg[i] : 0;
  lds[threadIdx.x] = v;
  __syncthreads();
  for (int off = 1; off < 1024; off <<= 1) {
    int t = (threadIdx.x >= (unsigned)off) ? lds[threadIdx.x - off] : 0;
    __syncthreads();
    lds[threadIdx.x] += t;
    __syncthreads();
  }
  if (i < N) rowptr[i + 1] = lds[threadIdx.x];
  if (threadIdx.x == 1023) partial[blockIdx.x] = lds[1023];
}

__global__ __launch_bounds__(128) void scan2_kernel(int* __restrict__ partial, int B) {
  __shared__ int lds[128];
  int t = threadIdx.x;
  int v = (t < B) ? partial[t] : 0;
  lds[t] = v;
  __syncthreads();
  for (int off = 1; off < 128; off <<= 1) {
    int tv = (t >= off) ? lds[t - off] : 0;
    __syncthreads();
    lds[t] += tv;
    __syncthreads();
  }
  if (t < B) partial[t] = lds[t] - v;               // exclusive
}

__global__ __launch_bounds__(1024) void scan3_kernel(const int* __restrict__ deg,
                                                     int* __restrict__ rowptr,
                                                     const int* __restrict__ partial,
                                                     int* __restrict__ cursor, int N) {
  int i = blockIdx.x * 1024 + threadIdx.x;
  if (i < N) {
    int r = rowptr[i + 1] + partial[blockIdx.x];
    rowptr[i + 1] = r;
    cursor[i] = r - deg[i];
    if (i == 0) rowptr[0] = 0;
  }
}

// ---------------- phase-2 fill: bucket-local scatter into exact CSR ----------------
__global__ __launch_bounds__(256) void fill2_kernel(const int2* __restrict__ stage,
                                                    const int* __restrict__ bbase,
                                                    const int* __restrict__ bcur,
                                                    int* __restrict__ cursor,
                                                    const float* __restrict__ dinv,
                                                    int2* __restrict__ colw) {
  const int b = blockIdx.x >> 1;
  const int half = blockIdx.x & 1;
  const int lo = bbase[b];
  const int hi = bcur[b];
  for (int i = lo + half * 256 + threadIdx.x; i < hi; i += 512) {
    int2 sd = stage[i];
    int slot = atomicAdd(&cursor[sd.y], 1);
    colw[slot] = make_int2(sd.x, __float_as_int(dinv[sd.x] * dinv[sd.y]));
  }
}

// ---------------- fallback path (small ws): direct atomics ----------------
__global__ __launch_bounds__(256) void deg_atomic_kernel(const int* __restrict__ ei, int E,
                                                         const int* __restrict__ flag,
                                                         int* __restrict__ deg) {
  int e = blockIdx.x * 256 + threadIdx.x;
  if (e >= E) return;
  const int is64 = *flag;
  int d = is64 ? ei[2 * (E + e)] : ei[E + e];
  atomicAdd(&deg[d], 1);
}
__global__ __launch_bounds__(256) void dinv_kernel(const int* __restrict__ deg,
                                                   float* __restrict__ dinv, int N) {
  int i = blockIdx.x * 256 + threadIdx.x;
  if (i < N) dinv[i] = rsqrtf((float)(deg[i] + 1));
}
__global__ __launch_bounds__(256) void fill_direct_kernel(const int* __restrict__ ei, int E,
                                                          const int* __restrict__ flag,
                                                          const float* __restrict__ dinv,
                                                          int* __restrict__ cursor,
                                                          int2* __restrict__ colw) {
  int e = blockIdx.x * 256 + threadIdx.x;
  if (e >= E) return;
  const int is64 = *flag;
  int s = is64 ? ei[2 * e] : ei[e];
  int d = is64 ? ei[2 * (E + e)] : ei[E + e];
  int slot = atomicAdd(&cursor[d], 1);
  colw[slot] = make_int2(s, __float_as_int(dinv[s] * dinv[d]));
}

// ---------------- cast f32 -> bf16 table ----------------
__global__ __launch_bounds__(256) void cast_kernel(const float* __restrict__ in,
                                                   ushort* __restrict__ out, int total) {
  int i = (blockIdx.x * 256 + threadIdx.x) * 4;
  if (i >= total) return;
  float4 v = *(const float4*)(in + i);
  ushort4 o;
  o.x = f2bf_bits(v.x);
  o.y = f2bf_bits(v.y);
  o.z = f2bf_bits(v.z);
  o.w = f2bf_bits(v.w);
  *(ushort4*)(out + i) = o;
}

// ---------------- aggregation: 4 dst per wave, 16 lanes x 4 features ----------
// out[dst] = dinv^2 * f(H[dst]) + sum w * f(H[src]); f = relu(a*x+c) if BN.
// Each 16-lane group owns one dst; lane loads ushort4 (4 features).
// One gather instruction serves 4 edges (4 groups).
template <bool BN>
__global__ __launch_bounds__(256) void agg_kernel(const ushort* __restrict__ H,
                                                  const int* __restrict__ rowptr,
                                                  const int2* __restrict__ colw,
                                                  const float* __restrict__ dinv,
                                                  const float* __restrict__ stats,
                                                  const float* __restrict__ g,
                                                  const float* __restrict__ be,
                                                  ushort* __restrict__ out, int N) {
  const int lane = threadIdx.x & 63;
  const int wid = threadIdx.x >> 6;
  const int grp = lane >> 4;   // 0..3: which dst of this wave
  const int fl = lane & 15;    // feature block: features fl*4 .. fl*4+3
  const int dst = (blockIdx.x * 4 + wid) * 4 + grp;
  const bool live = dst < N;
  const int dc = live ? dst : N - 1;

  float a[4], cc[4];
  if (BN) {
    const float invN = 1.0f / (float)N;
#pragma unroll
    for (int j = 0; j < 4; ++j) {
      int f = fl * 4 + j;
      float m = stats[f] * invN;
      float v = stats[64 + f] * invN - m * m;
      float r = rsqrtf(v + EPSF);
      a[j] = g[f] * r;
      cc[j] = be[f] - m * a[j];
    }
  }

  const int e0 = rowptr[dc];
  const int e1 = live ? rowptr[dc + 1] : e0;
  const float di = dinv[dc];

  float acc[4][4];
#pragma unroll
  for (int u = 0; u < 4; ++u)
#pragma unroll
    for (int j = 0; j < 4; ++j) acc[u][j] = 0.f;

  // self-loop term
  {
    uint2 uv = *(const uint2*)(H + (size_t)dc * FD + fl * 4);
    float h0 = __uint_as_float(uv.x << 16);
    float h1 = __uint_as_float(uv.x & 0xffff0000u);
    float h2 = __uint_as_float(uv.y << 16);
    float h3 = __uint_as_float(uv.y & 0xffff0000u);
    if (BN) {
      h0 = fmaxf(fmaf(a[0], h0, cc[0]), 0.f);
      h1 = fmaxf(fmaf(a[1], h1, cc[1]), 0.f);
      h2 = fmaxf(fmaf(a[2], h2, cc[2]), 0.f);
      h3 = fmaxf(fmaf(a[3], h3, cc[3]), 0.f);
    }
    const float dsq = di * di;
    acc[0][0] = dsq * h0;
    acc[0][1] = dsq * h1;
    acc[0][2] = dsq * h2;
    acc[0][3] = dsq * h3;
  }

  for (int base = e0; __any(base < e1); base += 4) {
#pragma unroll
    for (int u = 0; u < 4; ++u) {
      const int ee = base + u;
      const bool valid = ee < e1;
      const int idx = valid ? ee : 0;      // colw[0] always exists; w masked
      const int2 cw = colw[idx];
      const float w = valid ? __int_as_float(cw.y) : 0.f;
      uint2 uv = *(const uint2*)(H + (size_t)cw.x * FD + fl * 4);
      float h0 = __uint_as_float(uv.x << 16);
      float h1 = __uint_as_float(uv.x & 0xffff0000u);
      float h2 = __uint_as_float(uv.y << 16);
      float h3 = __uint_as_float(uv.y & 0xffff0000u);
      if (BN) {
        h0 = fmaxf(fmaf(a[0], h0, cc[0]), 0.f);
        h1 = fmaxf(fmaf(a[1], h1, cc[1]), 0.f);
        h2 = fmaxf(fmaf(a[2], h2, cc[2]), 0.f);
        h3 = fmaxf(fmaf(a[3], h3, cc[3]), 0.f);
      }
      acc[u][0] = fmaf(w, h0, acc[u][0]);
      acc[u][1] = fmaf(w, h1, acc[u][1]);
      acc[u][2] = fmaf(w, h2, acc[u][2]);
      acc[u][3] = fmaf(w, h3, acc[u][3]);
    }
  }

  if (live) {
    ushort4 o;
    o.x = f2bf_bits((acc[0][0] + acc[1][0]) + (acc[2][0] + acc[3][0]));
    o.y = f2bf_bits((acc[0][1] + acc[1][1]) + (acc[2][1] + acc[3][1]));
    o.z = f2bf_bits((acc[0][2] + acc[1][2]) + (acc[2][2] + acc[3][2]));
    o.w = f2bf_bits((acc[0][3] + acc[1][3]) + (acc[2][3] + acc[3][3]));
    *(ushort4*)(out + (size_t)dst * FD + fl * 4) = o;
  }
}

// ---------------- MFMA GEMM: out = A(bf16) @ W + b -------------------------
template <bool BF16OUT>
__global__ __launch_bounds__(256) void gemm_mfma_kernel(const ushort* __restrict__ A,
                                                        const float* __restrict__ W,
                                                        const float* __restrict__ bias,
                                                        ushort* __restrict__ outb,
                                                        float* __restrict__ outf,
                                                        float* __restrict__ stats, int N) {
  const int lane = threadIdx.x & 63;
  const int wid = threadIdx.x >> 6;
  const int lo = lane & 15;
  const int hi = lane >> 4;

  __shared__ float sred[128];
  if (BF16OUT) {
    if (threadIdx.x < 128) sred[threadIdx.x] = 0.f;
    __syncthreads();
  }

  bf16x8 bfrag[2][4];
#pragma unroll
  for (int kk = 0; kk < 2; ++kk)
#pragma unroll
    for (int nt = 0; nt < 4; ++nt)
#pragma unroll
      for (int j = 0; j < 8; ++j) {
        int k = kk * 32 + hi * 8 + j;
        bfrag[kk][nt][j] = (short)f2bf_bits(W[k * FD + nt * 16 + lo]);
      }

  float bl[4];
#pragma unroll
  for (int nt = 0; nt < 4; ++nt) bl[nt] = bias[nt * 16 + lo];

  float s1[4] = {0.f, 0.f, 0.f, 0.f};
  float s2[4] = {0.f, 0.f, 0.f, 0.f};

  const int TILES = (N + 15) / 16;
  const int stride = gridDim.x * 4;
  for (int tile = blockIdx.x * 4 + wid; tile < TILES; tile += stride) {
    const int row0 = tile * 16;
    const int ar = min(row0 + lo, N - 1);
    const ushort* ap = A + (size_t)ar * FD + hi * 8;
    bf16x8 a0 = *(const bf16x8*)ap;
    bf16x8 a1 = *(const bf16x8*)(ap + 32);

    f32x4 acc[4] = {{0.f, 0.f, 0.f, 0.f},
                    {0.f, 0.f, 0.f, 0.f},
                    {0.f, 0.f, 0.f, 0.f},
                    {0.f, 0.f, 0.f, 0.f}};
#pragma unroll
    for (int nt = 0; nt < 4; ++nt) {
      acc[nt] = __builtin_amdgcn_mfma_f32_16x16x32_bf16(a0, bfrag[0][nt], acc[nt], 0, 0, 0);
      acc[nt] = __builtin_amdgcn_mfma_f32_16x16x32_bf16(a1, bfrag[1][nt], acc[nt], 0, 0, 0);
    }

#pragma unroll
    for (int nt = 0; nt < 4; ++nt) {
#pragma unroll
      for (int r = 0; r < 4; ++r) {
        int row = row0 + hi * 4 + r;
        if (row < N) {
          float o = acc[nt][r] + bl[nt];
          if (BF16OUT) {
            outb[(size_t)row * FD + nt * 16 + lo] = f2bf_bits(o);
            s1[nt] += o;
            s2[nt] += o * o;
          } else {
            outf[(size_t)row * FD + nt * 16 + lo] = o;
          }
        }
      }
    }
  }

  if (BF16OUT) {
#pragma unroll
    for (int nt = 0; nt < 4; ++nt) {
      atomicAdd(&sred[nt * 16 + lo], s1[nt]);
      atomicAdd(&sred[64 + nt * 16 + lo], s2[nt]);
    }
    __syncthreads();
    if (threadIdx.x < 128) atomicAdd(&stats[threadIdx.x], sred[threadIdx.x]);
  }
}

extern "C" void kernel_launch(void* const* d_in, const int* in_sizes, int n_in,
                              void* d_out, int out_size, void* d_ws, size_t ws_size,
                              hipStream_t stream) {
  const float* x = (const float*)d_in[0];
  const int* ei = (const int*)d_in[1];
  const float* W1 = (const float*)d_in[2];
  const float* b1 = (const float*)d_in[3];
  const float* g1 = (const float*)d_in[4];
  const float* be1 = (const float*)d_in[5];
  const float* W2 = (const float*)d_in[6];
  const float* b2 = (const float*)d_in[7];
  const float* g2 = (const float*)d_in[8];
  const float* be2 = (const float*)d_in[9];
  const float* W3 = (const float*)d_in[10];
  const float* b3 = (const float*)d_in[11];

  const int N = in_sizes[0] / FD;
  const int E = in_sizes[1] / 2;
  const int nB = (N + BWID - 1) >> BSHIFT;  // used buckets

  char* p = (char*)d_ws;
  auto alloc = [&](size_t bytes) {
    char* r = p;
    p += (bytes + 255) & ~(size_t)255;
    return r;
  };
  int* flag = (int*)alloc(4);
  float* stats1 = (float*)alloc(128 * 4);
  float* stats2 = (float*)alloc(128 * 4);
  int* partial = (int*)alloc(128 * 4);
  int* bhist = (int*)alloc(NBUCK * 4);
  int* bbase = (int*)alloc(NBUCK * 4);
  int* bcur = (int*)alloc(NBUCK * 4);
  int* deg = (int*)alloc((size_t)N * 4);
  float* dinv = (float*)alloc((size_t)N * 4);
  int* rowptr = (int*)alloc((size_t)(N + 1) * 4);
  int* cursor = (int*)alloc((size_t)N * 4);
  int2* colw = (int2*)alloc((size_t)E * 8);
  ushort* T0 = (ushort*)alloc((size_t)N * FD * 2);
  ushort* T1 = (ushort*)alloc((size_t)N * FD * 2);
  size_t base_need = (size_t)(p - (char*)d_ws);
  int2* stage = (int2*)alloc((size_t)E * 8);
  size_t full_need = (size_t)(p - (char*)d_ws);
  const bool two_phase =
      ((ws_size == 0) || (ws_size >= full_need)) && (N <= NBUCK * BWID);
  (void)base_need;

  const int NB = (N + 1023) / 1024;
  const int EB = (E + P1_EDGES - 1) / P1_EDGES;

  init_kernel<<<1, 256, 0, stream>>>(ei, flag, bhist, stats1, stats2);

  if (two_phase) {
    hist_kernel<<<EB, 256, 0, stream>>>(ei, E, flag, bhist);
    bscan_kernel<<<1, NBUCK, 0, stream>>>(bhist, bbase, bcur);
    fill1_kernel<<<EB, 256, 0, stream>>>(ei, E, flag, bcur, stage);
    degcount_kernel<<<nB, 256, 0, stream>>>(stage, bbase, bcur, deg, dinv, N);
    scan1_kernel<<<NB, 1024, 0, stream>>>(deg, rowptr, partial, N);
    scan2_kernel<<<1, 128, 0, stream>>>(partial, NB);
    scan3_kernel<<<NB, 1024, 0, stream>>>(deg, rowptr, partial, cursor, N);
    fill2_kernel<<<2 * nB, 256, 0, stream>>>(stage, bbase, bcur, cursor, dinv, colw);
  } else {
    hipMemsetAsync(deg, 0, (size_t)N * 4, stream);
    deg_atomic_kernel<<<(E + 255) / 256, 256, 0, stream>>>(ei, E, flag, deg);
    dinv_kernel<<<(N + 255) / 256, 256, 0, stream>>>(deg, dinv, N);
    scan1_kernel<<<NB, 1024, 0, stream>>>(deg, rowptr, partial, N);
    scan2_kernel<<<1, 128, 0, stream>>>(partial, NB);
    scan3_kernel<<<NB, 1024, 0, stream>>>(deg, rowptr, partial, cursor, N);
    fill_direct_kernel<<<(E + 255) / 256, 256, 0, stream>>>(ei, E, flag, dinv, cursor,
                                                            colw);
  }

  const int aggGrid = (N + 15) / 16;  // 4 waves/block x 4 dst/wave
  const int castGrid = (N * FD / 4 + 255) / 256;
  const int TILES = (N + 15) / 16;
  const int gemmGrid = (TILES + 15) / 16;

  // layer 1
  cast_kernel<<<castGrid, 256, 0, stream>>>(x, T0, N * FD);
  agg_kernel<false><<<aggGrid, 256, 0, stream>>>(T0, rowptr, colw, dinv, nullptr, nullptr,
                                                 nullptr, T1, N);
  gemm_mfma_kernel<true><<<gemmGrid, 256, 0, stream>>>(T1, W1, b1, T0, nullptr, stats1, N);

  // layer 2
  agg_kernel<true><<<aggGrid, 256, 0, stream>>>(T0, rowptr, colw, dinv, stats1, g1, be1,
                                                T1, N);
  gemm_mfma_kernel<true><<<gemmGrid, 256, 0, stream>>>(T1, W2, b2, T0, nullptr, stats2, N);

  // layer 3: final GEMM -> f32 d_out
  agg_kernel<true><<<aggGrid, 256, 0, stream>>>(T0, rowptr, colw, dinv, stats2, g2, be2,
                                                T1, N);
  gemm_mfma_kernel<false><<<gemmGrid, 256, 0, stream>>>(T1, W3, b3, nullptr,
                                                        (float*)d_out, nullptr, N);
}

// Round 7
// 308.912 us; speedup vs baseline: 2.2382x; 1.0270x over previous
//
#include <hip/hip_runtime.h>
#include <hip/hip_bf16.h>

// GCN 3-layer fused pipeline for MI355X.
// Â(xW) == (Âx)W ; CSR built per call; BN+ReLU as separate in-place pass.
// R7: (1) BN+ReLU hoisted out of agg (bnrelu in-place pass),
//     (2) agg: 16-lane group = 2x8-lane subgroups, uint4 gathers (8 edges/step),
//     (3) degscan: fused per-bucket degree+scan -> rowptr+cursor (kills 3 kernels).

#define FD 64
#define EPSF 1e-5f

#define NBUCK 256        // max buckets (bucket = dst >> BSHIFT)
#define BSHIFT 9
#define BWID 512         // nodes per bucket (pow2); supports N <= 131072
#define SLOTS 28         // LDS slots per bucket in fill1 (256*28*8 = 57 KiB)
#define P1_EDGES 4096

typedef __attribute__((ext_vector_type(8))) short bf16x8;
typedef __attribute__((ext_vector_type(4))) float f32x4;

__device__ __forceinline__ ushort f2bf_bits(float f) {
  __hip_bfloat16 h = __float2bfloat16(f);
  return *(ushort*)&h;
}
__device__ __forceinline__ unsigned packbf(float lo, float hi) {
  return (unsigned)f2bf_bits(lo) | ((unsigned)f2bf_bits(hi) << 16);
}

// ---------------- init: edge-width detect + zero bhist/stats ----------------
__global__ __launch_bounds__(256) void init_kernel(const int* __restrict__ ei,
                                                   int* __restrict__ flag,
                                                   int* __restrict__ bhist,
                                                   float* __restrict__ stats1,
                                                   float* __restrict__ stats2) {
  int t = threadIdx.x;
  bhist[t] = 0;
  if (t < 128) {
    stats1[t] = 0.f;
    stats2[t] = 0.f;
  }
  if (t < 64) {
    int v = ei[2 * t + 1];
    unsigned long long nz = __ballot(v != 0);
    if (t == 0) *flag = (nz == 0ull) ? 1 : 0;
  }
}

// ---------------- bucket histogram of dst ----------------
__global__ __launch_bounds__(256) void hist_kernel(const int* __restrict__ ei, int E,
                                                   const int* __restrict__ flag,
                                                   int* __restrict__ bhist) {
  __shared__ int h[NBUCK];
  const int tid = threadIdx.x;
  h[tid] = 0;
  __syncthreads();
  const int is64 = *flag;
  const int base = blockIdx.x * P1_EDGES;
#pragma unroll 1
  for (int k = 0; k < P1_EDGES / 256; ++k) {
    int e = base + k * 256 + tid;
    if (e < E) {
      int d = is64 ? ei[2 * (E + e)] : ei[E + e];
      atomicAdd(&h[d >> BSHIFT], 1);
    }
  }
  __syncthreads();
  if (h[tid]) atomicAdd(&bhist[tid], h[tid]);
}

// ---------------- exclusive scan of 256 bucket counts -> stage bases ----------
__global__ __launch_bounds__(256) void bscan_kernel(const int* __restrict__ bhist,
                                                    int* __restrict__ bbase,
                                                    int* __restrict__ bcur) {
  __shared__ int lds[NBUCK];
  int t = threadIdx.x;
  int v = bhist[t];
  lds[t] = v;
  __syncthreads();
  for (int off = 1; off < NBUCK; off <<= 1) {
    int tv = (t >= off) ? lds[t - off] : 0;
    __syncthreads();
    lds[t] += tv;
    __syncthreads();
  }
  int ex = lds[t] - v;  // exclusive
  bbase[t] = ex;
  bcur[t] = ex;
}

// ---------------- phase-1 fill: LDS-binned staging (s, d) ----------------
__global__ __launch_bounds__(256) void fill1_kernel(const int* __restrict__ ei, int E,
                                                    const int* __restrict__ flag,
                                                    int* __restrict__ bcur,
                                                    int2* __restrict__ stage) {
  __shared__ int2 sbuf[NBUCK][SLOTS];
  __shared__ int scnt[NBUCK];
  __shared__ int sbase[NBUCK];
  const int tid = threadIdx.x;
  scnt[tid] = 0;
  __syncthreads();
  const int is64 = *flag;
  const int base = blockIdx.x * P1_EDGES;
#pragma unroll 1
  for (int k = 0; k < P1_EDGES / 256; ++k) {
    int e = base + k * 256 + tid;
    if (e < E) {
      int s = is64 ? ei[2 * e] : ei[e];
      int d = is64 ? ei[2 * (E + e)] : ei[E + e];
      int b = d >> BSHIFT;
      int pos = atomicAdd(&scnt[b], 1);
      if (pos < SLOTS) {
        sbuf[b][pos] = make_int2(s, d);
      } else {
        stage[atomicAdd(&bcur[b], 1)] = make_int2(s, d);  // rare overflow
      }
    }
  }
  __syncthreads();
  {
    int c = scnt[tid];
    if (c > SLOTS) c = SLOTS;
    scnt[tid] = c;
    sbase[tid] = c ? atomicAdd(&bcur[tid], c) : 0;
  }
  __syncthreads();
  for (int idx = tid; idx < NBUCK * SLOTS; idx += 256) {
    int b = idx / SLOTS, sl = idx - b * SLOTS;
    if (sl < scnt[b]) stage[sbase[b] + sl] = sbuf[b][sl];
  }
}

// ------- degscan: per-bucket hist + LDS scan -> rowptr, cursor, dinv --------
// rowptr[n] = bbase[bucket] + (# staged edges with dst < n within bucket).
__global__ __launch_bounds__(256) void degscan_kernel(const int2* __restrict__ stage,
                                                      const int* __restrict__ bbase,
                                                      const int* __restrict__ bcur,
                                                      int* __restrict__ rowptr,
                                                      int* __restrict__ cursor,
                                                      float* __restrict__ dinv,
                                                      int N, int nB) {
  __shared__ int h[BWID];
  __shared__ int ps[256];
  const int b = blockIdx.x;
  const int tid = threadIdx.x;
  h[tid] = 0;
  h[tid + 256] = 0;
  __syncthreads();
  const int lo = bbase[b], hi = bcur[b];
  for (int i = lo + tid; i < hi; i += 256)
    atomicAdd(&h[stage[i].y - (b << BSHIFT)], 1);
  __syncthreads();
  const int a0 = h[2 * tid], a1 = h[2 * tid + 1];
  ps[tid] = a0 + a1;
  __syncthreads();
  for (int off = 1; off < 256; off <<= 1) {
    int v = (tid >= off) ? ps[tid - off] : 0;
    __syncthreads();
    ps[tid] += v;
    __syncthreads();
  }
  const int excl = ps[tid] - (a0 + a1);
  const int n0 = b << BSHIFT;
  const int na = n0 + 2 * tid;
  const int nb2 = na + 1;
  if (na < N) {
    int r = lo + excl;
    rowptr[na] = r;
    cursor[na] = r;
    dinv[na] = rsqrtf((float)(a0 + 1));
  }
  if (nb2 < N) {
    int r = lo + excl + a0;
    rowptr[nb2] = r;
    cursor[nb2] = r;
    dinv[nb2] = rsqrtf((float)(a1 + 1));
  }
  if (b == nB - 1 && tid == 255) rowptr[N] = lo + ps[255];  // == E
}

// ---------------- phase-2 fill: bucket-local scatter into exact CSR ----------------
__global__ __launch_bounds__(256) void fill2_kernel(const int2* __restrict__ stage,
                                                    const int* __restrict__ bbase,
                                                    const int* __restrict__ bcur,
                                                    int* __restrict__ cursor,
                                                    const float* __restrict__ dinv,
                                                    int2* __restrict__ colw) {
  const int b = blockIdx.x >> 1;
  const int half = blockIdx.x & 1;
  const int lo = bbase[b];
  const int hi = bcur[b];
  for (int i = lo + half * 256 + threadIdx.x; i < hi; i += 512) {
    int2 sd = stage[i];
    int slot = atomicAdd(&cursor[sd.y], 1);
    colw[slot] = make_int2(sd.x, __float_as_int(dinv[sd.x] * dinv[sd.y]));
  }
}

// ---------------- fallback path (small ws): direct atomics + scans ----------------
__global__ __launch_bounds__(256) void deg_atomic_kernel(const int* __restrict__ ei, int E,
                                                         const int* __restrict__ flag,
                                                         int* __restrict__ deg) {
  int e = blockIdx.x * 256 + threadIdx.x;
  if (e >= E) return;
  const int is64 = *flag;
  int d = is64 ? ei[2 * (E + e)] : ei[E + e];
  atomicAdd(&deg[d], 1);
}
__global__ __launch_bounds__(256) void dinv_kernel(const int* __restrict__ deg,
                                                   float* __restrict__ dinv, int N) {
  int i = blockIdx.x * 256 + threadIdx.x;
  if (i < N) dinv[i] = rsqrtf((float)(deg[i] + 1));
}
__global__ __launch_bounds__(1024) void scan1_kernel(const int* __restrict__ deg,
                                                     int* __restrict__ rowptr,
                                                     int* __restrict__ partial, int N) {
  __shared__ int lds[1024];
  int i = blockIdx.x * 1024 + threadIdx.x;
  int v = (i < N) ? deg[i] : 0;
  lds[threadIdx.x] = v;
  __syncthreads();
  for (int off = 1; off < 1024; off <<= 1) {
    int t = (threadIdx.x >= (unsigned)off) ? lds[threadIdx.x - off] : 0;
    __syncthreads();
    lds[threadIdx.x] += t;
    __syncthreads();
  }
  if (i < N) rowptr[i + 1] = lds[threadIdx.x];
  if (threadIdx.x == 1023) partial[blockIdx.x] = lds[1023];
}
__global__ __launch_bounds__(128) void scan2_kernel(int* __restrict__ partial, int B) {
  __shared__ int lds[128];
  int t = threadIdx.x;
  int v = (t < B) ? partial[t] : 0;
  lds[t] = v;
  __syncthreads();
  for (int off = 1; off < 128; off <<= 1) {
    int tv = (t >= off) ? lds[t - off] : 0;
    __syncthreads();
    lds[t] += tv;
    __syncthreads();
  }
  if (t < B) partial[t] = lds[t] - v;  // exclusive
}
__global__ __launch_bounds__(1024) void scan3_kernel(const int* __restrict__ deg,
                                                     int* __restrict__ rowptr,
                                                     const int* __restrict__ partial,
                                                     int* __restrict__ cursor, int N) {
  int i = blockIdx.x * 1024 + threadIdx.x;
  if (i < N) {
    int r = rowptr[i + 1] + partial[blockIdx.x];
    rowptr[i + 1] = r;
    cursor[i] = r - deg[i];
    if (i == 0) rowptr[0] = 0;
  }
}
__global__ __launch_bounds__(256) void fill_direct_kernel(const int* __restrict__ ei, int E,
                                                          const int* __restrict__ flag,
                                                          const float* __restrict__ dinv,
                                                          int* __restrict__ cursor,
                                                          int2* __restrict__ colw) {
  int e = blockIdx.x * 256 + threadIdx.x;
  if (e >= E) return;
  const int is64 = *flag;
  int s = is64 ? ei[2 * e] : ei[e];
  int d = is64 ? ei[2 * (E + e)] : ei[E + e];
  int slot = atomicAdd(&cursor[d], 1);
  colw[slot] = make_int2(s, __float_as_int(dinv[s] * dinv[d]));
}

// ---------------- cast f32 -> bf16 table ----------------
__global__ __launch_bounds__(256) void cast_kernel(const float* __restrict__ in,
                                                   ushort* __restrict__ out, int total) {
  int i = (blockIdx.x * 256 + threadIdx.x) * 4;
  if (i >= total) return;
  float4 v = *(const float4*)(in + i);
  ushort4 o;
  o.x = f2bf_bits(v.x);
  o.y = f2bf_bits(v.y);
  o.z = f2bf_bits(v.z);
  o.w = f2bf_bits(v.w);
  *(ushort4*)(out + i) = o;
}

// ---------------- bnrelu: in-place T <- relu(a*T + c), a/c from batch stats ----
__global__ __launch_bounds__(256) void bnrelu_kernel(ushort* __restrict__ T,
                                                     const float* __restrict__ stats,
                                                     const float* __restrict__ g,
                                                     const float* __restrict__ be,
                                                     int N) {
  __shared__ float sa[FD], sc[FD];
  if (threadIdx.x < FD) {
    const float invN = 1.0f / (float)N;
    float m = stats[threadIdx.x] * invN;
    float v = stats[FD + threadIdx.x] * invN - m * m;
    float r = rsqrtf(v + EPSF);
    float a = g[threadIdx.x] * r;
    sa[threadIdx.x] = a;
    sc[threadIdx.x] = be[threadIdx.x] - m * a;
  }
  __syncthreads();
  const int idx = (blockIdx.x * 256 + threadIdx.x) * 8;  // ushort units
  if (idx >= N * FD) return;
  const int f0 = idx & (FD - 1);
  uint4 v = *(const uint4*)(T + idx);
  float h0 = __uint_as_float(v.x << 16);
  float h1 = __uint_as_float(v.x & 0xffff0000u);
  float h2 = __uint_as_float(v.y << 16);
  float h3 = __uint_as_float(v.y & 0xffff0000u);
  float h4 = __uint_as_float(v.z << 16);
  float h5 = __uint_as_float(v.z & 0xffff0000u);
  float h6 = __uint_as_float(v.w << 16);
  float h7 = __uint_as_float(v.w & 0xffff0000u);
  h0 = fmaxf(fmaf(sa[f0 + 0], h0, sc[f0 + 0]), 0.f);
  h1 = fmaxf(fmaf(sa[f0 + 1], h1, sc[f0 + 1]), 0.f);
  h2 = fmaxf(fmaf(sa[f0 + 2], h2, sc[f0 + 2]), 0.f);
  h3 = fmaxf(fmaf(sa[f0 + 3], h3, sc[f0 + 3]), 0.f);
  h4 = fmaxf(fmaf(sa[f0 + 4], h4, sc[f0 + 4]), 0.f);
  h5 = fmaxf(fmaf(sa[f0 + 5], h5, sc[f0 + 5]), 0.f);
  h6 = fmaxf(fmaf(sa[f0 + 6], h6, sc[f0 + 6]), 0.f);
  h7 = fmaxf(fmaf(sa[f0 + 7], h7, sc[f0 + 7]), 0.f);
  uint4 o;
  o.x = packbf(h0, h1);
  o.y = packbf(h2, h3);
  o.z = packbf(h4, h5);
  o.w = packbf(h6, h7);
  *(uint4*)(T + idx) = o;
}

// ---------------- aggregation: pure weighted gather-sum --------------------
// out[dst] = dinv[dst]^2 * H[dst] + sum_e w_e * H[src_e]
// Wave = 4 groups (16 lanes, one dst each); group = 2 subgroups (8 lanes,
// alternating edges); lane covers 8 features via uint4 (16B). 8 edges/step.
__global__ __launch_bounds__(256) void agg_kernel(const ushort* __restrict__ H,
                                                  const int* __restrict__ rowptr,
                                                  const int2* __restrict__ colw,
                                                  const float* __restrict__ dinv,
                                                  ushort* __restrict__ out, int N) {
  const int lane = threadIdx.x & 63;
  const int wid = threadIdx.x >> 6;
  const int grp = lane >> 4;        // 0..3: dst group
  const int sg = (lane >> 3) & 1;   // subgroup: edge parity
  const int fl8 = lane & 7;         // feature block: fl8*8 .. fl8*8+7
  const int dst = (blockIdx.x * 4 + wid) * 4 + grp;
  const bool live = dst < N;
  const int dc = live ? dst : N - 1;

  const int e0 = rowptr[dc];
  const int e1 = live ? rowptr[dc + 1] : e0;

  float acc[4][8];
#pragma unroll
  for (int u = 0; u < 4; ++u)
#pragma unroll
    for (int j = 0; j < 8; ++j) acc[u][j] = 0.f;

  for (int base = e0; __any(base < e1); base += 8) {
#pragma unroll
    for (int u = 0; u < 4; ++u) {
      const int ee = base + 2 * u + sg;
      const bool valid = ee < e1;
      const int idx = valid ? ee : 0;
      const int2 cw = colw[idx];
      const float w = valid ? __int_as_float(cw.y) : 0.f;
      const uint4 uv = *(const uint4*)(H + (size_t)cw.x * FD + fl8 * 8);
      acc[u][0] = fmaf(w, __uint_as_float(uv.x << 16), acc[u][0]);
      acc[u][1] = fmaf(w, __uint_as_float(uv.x & 0xffff0000u), acc[u][1]);
      acc[u][2] = fmaf(w, __uint_as_float(uv.y << 16), acc[u][2]);
      acc[u][3] = fmaf(w, __uint_as_float(uv.y & 0xffff0000u), acc[u][3]);
      acc[u][4] = fmaf(w, __uint_as_float(uv.z << 16), acc[u][4]);
      acc[u][5] = fmaf(w, __uint_as_float(uv.z & 0xffff0000u), acc[u][5]);
      acc[u][6] = fmaf(w, __uint_as_float(uv.w << 16), acc[u][6]);
      acc[u][7] = fmaf(w, __uint_as_float(uv.w & 0xffff0000u), acc[u][7]);
    }
  }

  float r[8];
#pragma unroll
  for (int j = 0; j < 8; ++j)
    r[j] = (acc[0][j] + acc[1][j]) + (acc[2][j] + acc[3][j]);
#pragma unroll
  for (int j = 0; j < 8; ++j) r[j] += __shfl_xor(r[j], 8);

  // self-loop term
  const float di = dinv[dc];
  const float dsq = di * di;
  const uint4 sv = *(const uint4*)(H + (size_t)dc * FD + fl8 * 8);
  r[0] = fmaf(dsq, __uint_as_float(sv.x << 16), r[0]);
  r[1] = fmaf(dsq, __uint_as_float(sv.x & 0xffff0000u), r[1]);
  r[2] = fmaf(dsq, __uint_as_float(sv.y << 16), r[2]);
  r[3] = fmaf(dsq, __uint_as_float(sv.y & 0xffff0000u), r[3]);
  r[4] = fmaf(dsq, __uint_as_float(sv.z << 16), r[4]);
  r[5] = fmaf(dsq, __uint_as_float(sv.z & 0xffff0000u), r[5]);
  r[6] = fmaf(dsq, __uint_as_float(sv.w << 16), r[6]);
  r[7] = fmaf(dsq, __uint_as_float(sv.w & 0xffff0000u), r[7]);

  if (live && sg == 0) {
    uint4 o;
    o.x = packbf(r[0], r[1]);
    o.y = packbf(r[2], r[3]);
    o.z = packbf(r[4], r[5]);
    o.w = packbf(r[6], r[7]);
    *(uint4*)(out + (size_t)dst * FD + fl8 * 8) = o;
  }
}

// ---------------- MFMA GEMM: out = A(bf16) @ W + b -------------------------
template <bool BF16OUT>
__global__ __launch_bounds__(256) void gemm_mfma_kernel(const ushort* __restrict__ A,
                                                        const float* __restrict__ W,
                                                        const float* __restrict__ bias,
                                                        ushort* __restrict__ outb,
                                                        float* __restrict__ outf,
                                                        float* __restrict__ stats, int N) {
  const int lane = threadIdx.x & 63;
  const int wid = threadIdx.x >> 6;
  const int lo = lane & 15;
  const int hi = lane >> 4;

  __shared__ float sred[128];
  if (BF16OUT) {
    if (threadIdx.x < 128) sred[threadIdx.x] = 0.f;
    __syncthreads();
  }

  bf16x8 bfrag[2][4];
#pragma unroll
  for (int kk = 0; kk < 2; ++kk)
#pragma unroll
    for (int nt = 0; nt < 4; ++nt)
#pragma unroll
      for (int j = 0; j < 8; ++j) {
        int k = kk * 32 + hi * 8 + j;
        bfrag[kk][nt][j] = (short)f2bf_bits(W[k * FD + nt * 16 + lo]);
      }

  float bl[4];
#pragma unroll
  for (int nt = 0; nt < 4; ++nt) bl[nt] = bias[nt * 16 + lo];

  float s1[4] = {0.f, 0.f, 0.f, 0.f};
  float s2[4] = {0.f, 0.f, 0.f, 0.f};

  const int TILES = (N + 15) / 16;
  const int stride = gridDim.x * 4;
  for (int tile = blockIdx.x * 4 + wid; tile < TILES; tile += stride) {
    const int row0 = tile * 16;
    const int ar = min(row0 + lo, N - 1);
    const ushort* ap = A + (size_t)ar * FD + hi * 8;
    bf16x8 a0 = *(const bf16x8*)ap;
    bf16x8 a1 = *(const bf16x8*)(ap + 32);

    f32x4 acc[4] = {{0.f, 0.f, 0.f, 0.f},
                    {0.f, 0.f, 0.f, 0.f},
                    {0.f, 0.f, 0.f, 0.f},
                    {0.f, 0.f, 0.f, 0.f}};
#pragma unroll
    for (int nt = 0; nt < 4; ++nt) {
      acc[nt] = __builtin_amdgcn_mfma_f32_16x16x32_bf16(a0, bfrag[0][nt], acc[nt], 0, 0, 0);
      acc[nt] = __builtin_amdgcn_mfma_f32_16x16x32_bf16(a1, bfrag[1][nt], acc[nt], 0, 0, 0);
    }

#pragma unroll
    for (int nt = 0; nt < 4; ++nt) {
#pragma unroll
      for (int r = 0; r < 4; ++r) {
        int row = row0 + hi * 4 + r;
        if (row < N) {
          float o = acc[nt][r] + bl[nt];
          if (BF16OUT) {
            outb[(size_t)row * FD + nt * 16 + lo] = f2bf_bits(o);
            s1[nt] += o;
            s2[nt] += o * o;
          } else {
            outf[(size_t)row * FD + nt * 16 + lo] = o;
          }
        }
      }
    }
  }

  if (BF16OUT) {
#pragma unroll
    for (int nt = 0; nt < 4; ++nt) {
      atomicAdd(&sred[nt * 16 + lo], s1[nt]);
      atomicAdd(&sred[64 + nt * 16 + lo], s2[nt]);
    }
    __syncthreads();
    if (threadIdx.x < 128) atomicAdd(&stats[threadIdx.x], sred[threadIdx.x]);
  }
}

extern "C" void kernel_launch(void* const* d_in, const int* in_sizes, int n_in,
                              void* d_out, int out_size, void* d_ws, size_t ws_size,
                              hipStream_t stream) {
  const float* x = (const float*)d_in[0];
  const int* ei = (const int*)d_in[1];
  const float* W1 = (const float*)d_in[2];
  const float* b1 = (const float*)d_in[3];
  const float* g1 = (const float*)d_in[4];
  const float* be1 = (const float*)d_in[5];
  const float* W2 = (const float*)d_in[6];
  const float* b2 = (const float*)d_in[7];
  const float* g2 = (const float*)d_in[8];
  const float* be2 = (const float*)d_in[9];
  const float* W3 = (const float*)d_in[10];
  const float* b3 = (const float*)d_in[11];

  const int N = in_sizes[0] / FD;
  const int E = in_sizes[1] / 2;
  const int nB = (N + BWID - 1) >> BSHIFT;  // used buckets

  char* p = (char*)d_ws;
  auto alloc = [&](size_t bytes) {
    char* r = p;
    p += (bytes + 255) & ~(size_t)255;
    return r;
  };
  int* flag = (int*)alloc(4);
  float* stats1 = (float*)alloc(128 * 4);
  float* stats2 = (float*)alloc(128 * 4);
  int* partial = (int*)alloc(128 * 4);
  int* bhist = (int*)alloc(NBUCK * 4);
  int* bbase = (int*)alloc(NBUCK * 4);
  int* bcur = (int*)alloc(NBUCK * 4);
  int* deg = (int*)alloc((size_t)N * 4);
  float* dinv = (float*)alloc((size_t)N * 4);
  int* rowptr = (int*)alloc((size_t)(N + 1) * 4);
  int* cursor = (int*)alloc((size_t)N * 4);
  int2* colw = (int2*)alloc((size_t)E * 8);
  ushort* T0 = (ushort*)alloc((size_t)N * FD * 2);
  ushort* T1 = (ushort*)alloc((size_t)N * FD * 2);
  size_t base_need = (size_t)(p - (char*)d_ws);
  int2* stage = (int2*)alloc((size_t)E * 8);
  size_t full_need = (size_t)(p - (char*)d_ws);
  const bool two_phase =
      ((ws_size == 0) || (ws_size >= full_need)) && (N <= NBUCK * BWID);
  (void)base_need;

  const int NB = (N + 1023) / 1024;
  const int EB = (E + P1_EDGES - 1) / P1_EDGES;

  init_kernel<<<1, 256, 0, stream>>>(ei, flag, bhist, stats1, stats2);

  if (two_phase) {
    hist_kernel<<<EB, 256, 0, stream>>>(ei, E, flag, bhist);
    bscan_kernel<<<1, NBUCK, 0, stream>>>(bhist, bbase, bcur);
    fill1_kernel<<<EB, 256, 0, stream>>>(ei, E, flag, bcur, stage);
    degscan_kernel<<<nB, 256, 0, stream>>>(stage, bbase, bcur, rowptr, cursor, dinv, N,
                                           nB);
    fill2_kernel<<<2 * nB, 256, 0, stream>>>(stage, bbase, bcur, cursor, dinv, colw);
  } else {
    hipMemsetAsync(deg, 0, (size_t)N * 4, stream);
    deg_atomic_kernel<<<(E + 255) / 256, 256, 0, stream>>>(ei, E, flag, deg);
    dinv_kernel<<<(N + 255) / 256, 256, 0, stream>>>(deg, dinv, N);
    scan1_kernel<<<NB, 1024, 0, stream>>>(deg, rowptr, partial, N);
    scan2_kernel<<<1, 128, 0, stream>>>(partial, NB);
    scan3_kernel<<<NB, 1024, 0, stream>>>(deg, rowptr, partial, cursor, N);
    fill_direct_kernel<<<(E + 255) / 256, 256, 0, stream>>>(ei, E, flag, dinv, cursor,
                                                            colw);
  }

  const int aggGrid = (N + 15) / 16;  // 4 waves/block x 4 dst/wave
  const int castGrid = (N * FD / 4 + 255) / 256;
  const int bnGrid = (N * FD / 8 + 255) / 256;
  const int TILES = (N + 15) / 16;
  const int gemmGrid = (TILES + 15) / 16;

  // layer 1
  cast_kernel<<<castGrid, 256, 0, stream>>>(x, T0, N * FD);
  agg_kernel<<<aggGrid, 256, 0, stream>>>(T0, rowptr, colw, dinv, T1, N);
  gemm_mfma_kernel<true><<<gemmGrid, 256, 0, stream>>>(T1, W1, b1, T0, nullptr, stats1, N);

  // layer 2
  bnrelu_kernel<<<bnGrid, 256, 0, stream>>>(T0, stats1, g1, be1, N);
  agg_kernel<<<aggGrid, 256, 0, stream>>>(T0, rowptr, colw, dinv, T1, N);
  gemm_mfma_kernel<true><<<gemmGrid, 256, 0, stream>>>(T1, W2, b2, T0, nullptr, stats2, N);

  // layer 3
  bnrelu_kernel<<<bnGrid, 256, 0, stream>>>(T0, stats2, g2, be2, N);
  agg_kernel<<<aggGrid, 256, 0, stream>>>(T0, rowptr, colw, dinv, T1, N);
  gemm_mfma_kernel<false><<<gemmGrid, 256, 0, stream>>>(T1, W3, b3, nullptr,
                                                        (float*)d_out, nullptr, N);
}